// Round 1
// baseline (671.760 us; speedup 1.0000x reference)
//
#include <hip/hip_runtime.h>
#include <math.h>

#ifndef M_PI
#define M_PI 3.14159265358979323846
#endif

// ---------------- workspace layout (float offsets) ----------------
// consts
#define OFF_D1F 0                 // [16][64][31]            31744
#define OFF_D1I 31744             // [16][32][31][31]       492032
#define OFF_D2F 523776            // [8][32][15][15]         57600
#define OFF_S2  581376            // [8][15][15]              1800
// intermediates
#define OFF_XH  583176            // float2 [16][16*31]      15872 floats
#define OFF_XMN 599048            // float2 [16][32][32][225] 7372800 floats
#define OFF_XH2 7971848           // float2 [16*32][8][225]  1843200 floats
#define OFF_U   9815048           // float2 [16*32][8][225]  1843200 floats
#define OFF_FEAT 11658248         // [16][64]                 1024 floats
// total: 11,659,272 floats = ~46.6 MB

static __device__ __forceinline__ int iabs_(int v) { return v < 0 ? -v : v; }

// ---------------- K0: build Wigner-d constant tables (fp64) ----------------
__device__ double wig_d(int l, int m, int n, double beta, const double* LF) {
    int kmin = max(0, m - n), kmax = min(l + m, l - n);
    if (kmax < kmin) return 0.0;
    double cb = cos(0.5 * beta), sb = sin(0.5 * beta);
    double pref = 0.5 * (LF[l + m] + LF[l - m] + LF[l + n] + LF[l - n]);
    double lc = pref - LF[kmin] - LF[l + m - kmin] - LF[l - n - kmin] - LF[n - m + kmin];
    double t = exp(lc) * pow(cb, (double)(2 * l + m - n - 2 * kmin))
                       * pow(sb, (double)(n - m + 2 * kmin));
    if (kmin & 1) t = -t;
    double ratio = (sb * sb) / (cb * cb);
    double s = t;
    for (int k = kmin; k < kmax; ++k) {
        t *= -(((double)(l + m - k) * (double)(l - n - k)) /
               ((double)(k + 1) * (double)(n - m + k + 1))) * ratio;
        s += t;
    }
    return s;
}

__device__ double quadw_d(int j, int bq) {
    double beta = M_PI * (2.0 * j + 1.0) / (4.0 * bq);
    double s = 0.0;
    for (int k = 0; k < bq; ++k) s += sin((2.0 * k + 1.0) * beta) / (2.0 * k + 1.0);
    return 2.0 / bq * sin(beta) * s;
}

__global__ __launch_bounds__(256) void k0_consts(float* __restrict__ ws) {
    __shared__ double LF[64];
    int tid = threadIdx.x;
    if (tid < 64) LF[tid] = lgamma((double)tid + 1.0);
    __syncthreads();
    int gid = blockIdx.x * 256 + tid;
    if (gid >= 583176) return;

    if (gid < 31744) {                       // D1F [l][j][mh], l<16 j<64 mh<31
        int mh = gid % 31, j = (gid / 31) % 64, l = gid / (31 * 64);
        int m = mh - 15;
        double v = 0.0;
        if (iabs_(m) <= l) {
            double beta = M_PI * (2.0 * j + 1.0) / 128.0;
            v = quadw_d(j, 32) * wig_d(l, m, 0, beta, LF);
        }
        ws[OFF_D1F + gid] = (float)v;
    } else if (gid < 523776) {               // D1I [l][j][mh][nh], l<16 j<32
        int r = gid - 31744;
        int nh = r % 31, mh = (r / 31) % 31, j = (r / 961) % 32, l = r / (961 * 32);
        int m = mh - 15, n = nh - 15;
        double v = 0.0;
        if (iabs_(m) <= l && iabs_(n) <= l) {
            double beta = M_PI * (2.0 * j + 1.0) / 64.0;
            v = (2.0 * l + 1.0) * wig_d(l, m, n, beta, LF);
        }
        ws[OFF_D1I + r] = (float)v;
    } else if (gid < 581376) {               // D2F [l][j][mh][nh], l<8 j<32
        int r = gid - 523776;
        int nh = r % 15, mh = (r / 15) % 15, j = (r / 225) % 32, l = r / (225 * 32);
        int m = mh - 7, n = nh - 7;
        double v = 0.0;
        if (iabs_(m) <= l && iabs_(n) <= l) {
            double beta = M_PI * (2.0 * j + 1.0) / 64.0;
            v = quadw_d(j, 16) * wig_d(l, m, n, beta, LF);
        }
        ws[OFF_D2F + r] = (float)v;
    } else {                                 // S2 = D2I[:,0,:,:]  [l][mh][nh], l<8
        int r = gid - 581376;
        int nh = r % 15, mh = (r / 15) % 15, l = r / 225;
        int m = mh - 7, n = nh - 7;
        double v = 0.0;
        if (iabs_(m) <= l && iabs_(n) <= l) {
            double beta = M_PI / 32.0;       // beta2[0] = pi*(1)/(4*8)
            v = (2.0 * l + 1.0) * wig_d(l, m, n, beta, LF);
        }
        ws[OFF_S2 + r] = (float)v;
    }
}

// ---------------- K1: x -> xm (DFT over t, 31 freqs) -> xh ----------------
__global__ __launch_bounds__(256) void k1_xh(const float* __restrict__ x,
                                             const float* __restrict__ ws,
                                             float2* __restrict__ xh) {
    __shared__ float  xs[64 * 64];
    __shared__ float2 xm[64 * 31];   // [j][mh]
    __shared__ float2 cs64[64];
    int b = blockIdx.x, tid = threadIdx.x;
    for (int i = tid; i < 4096; i += 256) xs[i] = x[b * 4096 + i];
    if (tid < 64) {
        double a = 2.0 * M_PI * (double)tid / 64.0;
        cs64[tid] = make_float2((float)cos(a), (float)sin(a));
    }
    __syncthreads();
    for (int i = tid; i < 64 * 31; i += 256) {
        int mh = i % 31, j = i / 31;
        int mu = mh - 15;
        float re = 0.f, im = 0.f;
        for (int t = 0; t < 64; ++t) {
            float2 w = cs64[(mu * t) & 63];      // e^{-i th}: (c, -s)
            float xv = xs[j * 64 + t];
            re += xv * w.x;
            im -= xv * w.y;
        }
        xm[j * 31 + mh] = make_float2(re, im);
    }
    __syncthreads();
    const float* D1F = ws + OFF_D1F;
    for (int i = tid; i < 16 * 31; i += 256) {
        int mh = i % 31, l = i / 31;
        float re = 0.f, im = 0.f;
        for (int j = 0; j < 64; ++j) {
            float d = D1F[(l * 64 + j) * 31 + mh];
            float2 v = xm[j * 31 + mh];
            re += d * v.x;
            im += d * v.y;
        }
        xh[b * 496 + i] = make_float2(re, im);
    }
}

// ------- K2: per-(b,f,j) plane: f1 build -> iDFT2 -> relu -> fwd DFT2 15x15 -------
__global__ __launch_bounds__(256) void k2_planes(const float* __restrict__ w1r,
                                                 const float* __restrict__ w1i,
                                                 const float* __restrict__ ws,
                                                 float2* __restrict__ xmn) {
    __shared__ float2 A[496];    // xh[b]  [l][mh]
    __shared__ float2 W[496];    // conj(w1[f])*mask  [l][nh]
    __shared__ float2 f1[961];   // [mh][nh]
    __shared__ float2 tt[992];   // [mh][v]  31x32
    __shared__ float  ss[1024];  // [u][v]
    __shared__ float2 gg[480];   // [u][q]   32x15
    __shared__ float2 cs32[32];
    int j = blockIdx.x, f = blockIdx.y, b = blockIdx.z;
    int tid = threadIdx.x;
    const float2* xh = (const float2*)(ws + OFF_XH);
    const float*  D1I = ws + OFF_D1I;

    if (tid < 32) {
        double a = 2.0 * M_PI * (double)tid / 32.0;
        cs32[tid] = make_float2((float)cos(a), (float)sin(a));
    }
    for (int i = tid; i < 496; i += 256) {
        A[i] = xh[b * 496 + i];
        int l = i / 31, nh = i % 31;
        float mask = (iabs_(nh - 15) <= l) ? 1.0f : 0.0f;
        W[i] = make_float2(w1r[f * 496 + i] * mask, -w1i[f * 496 + i] * mask);
    }
    __syncthreads();
    // f1[m,n] = sum_l D1I[l,j,m,n] * A[l,m] * W[l,n]
    for (int i = tid; i < 961; i += 256) {
        int mh = i / 31, nh = i % 31;
        int lmin = max(iabs_(mh - 15), iabs_(nh - 15));
        float re = 0.f, im = 0.f;
        for (int l = lmin; l < 16; ++l) {
            float d = D1I[((l * 32 + j) * 31 + mh) * 31 + nh];
            float2 a = A[l * 31 + mh];
            float2 w = W[l * 31 + nh];
            re += d * (a.x * w.x - a.y * w.y);
            im += d * (a.x * w.y + a.y * w.x);
        }
        f1[i] = make_float2(re, im);
    }
    __syncthreads();
    // tt[m,v] = sum_n f1[m,n] e^{+2pi i (n-15) v / 32}
    for (int i = tid; i < 992; i += 256) {
        int mh = i >> 5, v = i & 31;
        float re = 0.f, im = 0.f;
        for (int nh = 0; nh < 31; ++nh) {
            float2 fv = f1[mh * 31 + nh];
            float2 w = cs32[((nh - 15) * v) & 31];
            re += fv.x * w.x - fv.y * w.y;
            im += fv.x * w.y + fv.y * w.x;
        }
        tt[i] = make_float2(re, im);
    }
    __syncthreads();
    // ss[u,v] = relu( Re sum_m tt[m,v] e^{+2pi i (m-15) u/32} )
    for (int i = tid; i < 1024; i += 256) {
        int u = i >> 5, v = i & 31;
        float acc = 0.f;
        for (int mh = 0; mh < 31; ++mh) {
            float2 tv = tt[mh * 32 + v];
            float2 w = cs32[((mh - 15) * u) & 31];
            acc += tv.x * w.x - tv.y * w.y;
        }
        ss[i] = fmaxf(acc, 0.0f);
    }
    __syncthreads();
    // gg[u,q] = sum_v ss[u,v] e^{-2pi i (q-7) v/32}
    for (int i = tid; i < 480; i += 256) {
        int u = i / 15, q = i % 15;
        int mu = q - 7;
        float re = 0.f, im = 0.f;
        for (int v = 0; v < 32; ++v) {
            float sv = ss[u * 32 + v];
            float2 w = cs32[(mu * v) & 31];
            re += sv * w.x;
            im -= sv * w.y;
        }
        gg[u * 15 + q] = make_float2(re, im);
    }
    __syncthreads();
    // h[p,q] = sum_u gg[u,q] e^{-2pi i (p-7) u/32}  -> xmn[b,f,j,p,q]
    for (int i = tid; i < 225; i += 256) {
        int p = i / 15, q = i % 15;
        int nu = p - 7;
        float re = 0.f, im = 0.f;
        for (int u = 0; u < 32; ++u) {
            float2 gv = gg[u * 15 + q];
            float2 w = cs32[(nu * u) & 31];
            re += gv.x * w.x + gv.y * w.y;
            im += gv.y * w.x - gv.x * w.y;
        }
        xmn[((size_t)((b * 32 + f) * 32 + j)) * 225 + i] = make_float2(re, im);
    }
}

// ---------------- K3: xh2[b,c,l,pq] = sum_j D2F[l,j,pq] * xmn[b,c,j,pq] ----------------
__global__ __launch_bounds__(256) void k3_xh2(const float* __restrict__ ws,
                                              const float2* __restrict__ xmn,
                                              float2* __restrict__ xh2) {
    int id = blockIdx.x * 256 + threadIdx.x;
    if (id >= 921600) return;
    int pq = id % 225;
    int l = (id / 225) % 8;
    int bc = id / 1800;
    const float* D2F = ws + OFF_D2F;
    float re = 0.f, im = 0.f;
    for (int j = 0; j < 32; ++j) {
        float d = D2F[(l * 32 + j) * 225 + pq];
        float2 v = xmn[((size_t)bc * 32 + j) * 225 + pq];
        re += d * v.x;
        im += d * v.y;
    }
    xh2[(size_t)bc * 1800 + l * 225 + pq] = make_float2(re, im);
}

// ---------------- K4: U[b,c,l,n,k] = sum_m S2[l,m,n] * xh2[b,c,l,m,k] ----------------
__global__ __launch_bounds__(256) void k4_U(const float* __restrict__ ws,
                                            const float2* __restrict__ xh2,
                                            float2* __restrict__ U) {
    int id = blockIdx.x * 256 + threadIdx.x;
    if (id >= 921600) return;
    int k = id % 15;
    int n = (id / 15) % 15;
    int l = (id / 225) % 8;
    int bc = id / 1800;
    const float* S2 = ws + OFF_S2;
    float re = 0.f, im = 0.f;
    for (int mh = 0; mh < 15; ++mh) {
        float s2 = S2[(l * 15 + mh) * 15 + n];
        float2 v = xh2[(size_t)bc * 1800 + l * 225 + mh * 15 + k];
        re += s2 * v.x;
        im += s2 * v.y;
    }
    U[(size_t)bc * 1800 + l * 225 + n * 15 + k] = make_float2(re, im);
}

// ---------------- K5: feat[b,f] = relu( sum real(U * conj(w2)) ) ----------------
__global__ __launch_bounds__(256) void k5_feat(const float* __restrict__ w2r,
                                               const float* __restrict__ w2i,
                                               const float2* __restrict__ U,
                                               float* __restrict__ feat) {
    int f = blockIdx.x, tid = threadIdx.x;
    float acc[16];
#pragma unroll
    for (int b = 0; b < 16; ++b) acc[b] = 0.f;
    for (int kk = tid; kk < 57600; kk += 256) {
        int nk = kk % 225;
        int l = (kk / 225) % 8;
        int c = kk / 1800;
        int n = nk / 15, k = nk % 15;
        if (iabs_(n - 7) > l || iabs_(k - 7) > l) continue;   // MASK2
        size_t wi = ((size_t)(c * 64 + f) * 8 + l) * 225 + nk;
        float wr = w2r[wi], wv = w2i[wi];
#pragma unroll
        for (int b = 0; b < 16; ++b) {
            float2 u = U[(size_t)(b * 32 + c) * 1800 + l * 225 + nk];
            acc[b] += u.x * wr + u.y * wv;   // real(u * conj(w))
        }
    }
    __shared__ float red[16][4];
    int lane = tid & 63, wave = tid >> 6;
#pragma unroll
    for (int b = 0; b < 16; ++b) {
        float v = acc[b];
        for (int off = 32; off > 0; off >>= 1) v += __shfl_down(v, off);
        if (lane == 0) red[b][wave] = v;
    }
    __syncthreads();
    if (tid < 16) {
        float s = red[tid][0] + red[tid][1] + red[tid][2] + red[tid][3];
        feat[tid * 64 + f] = fmaxf(s, 0.0f);
    }
}

// ---------------- K6: conv1d + relu + batchnorm + fc (single block) ----------------
__global__ __launch_bounds__(640) void k6_head(const float* __restrict__ feat,
                                               const float* __restrict__ w3,
                                               const float* __restrict__ b3,
                                               const float* __restrict__ gamma,
                                               const float* __restrict__ beta,
                                               const float* __restrict__ fcw,
                                               const float* __restrict__ fcb,
                                               float* __restrict__ out) {
    __shared__ float fL[1024];
    __shared__ float w3L[80];
    __shared__ float b3L[10];
    __shared__ float r3[9120];    // [ch][b*57+pos]
    __shared__ float scaleL[10], shiftL[10];
    int tid = threadIdx.x;
    for (int i = tid; i < 1024; i += 640) fL[i] = feat[i];
    if (tid < 80) w3L[tid] = w3[tid];
    if (tid >= 80 && tid < 90) b3L[tid - 80] = b3[tid - 80];
    __syncthreads();
    for (int i = tid; i < 9120; i += 640) {
        int ch = i / 912;
        int r = i % 912;
        int b = r / 57, pos = r % 57;
        float acc = b3L[ch];
#pragma unroll
        for (int t = 0; t < 8; ++t) acc += fL[b * 64 + pos + t] * w3L[ch * 8 + t];
        r3[ch * 912 + r] = fmaxf(acc, 0.0f);
    }
    __syncthreads();
    int wave = tid >> 6, lane = tid & 63;
    if (wave < 10) {
        float s = 0.f, s2 = 0.f;
        for (int i = lane; i < 912; i += 64) {
            float v = r3[wave * 912 + i];
            s += v;
            s2 += v * v;
        }
        for (int off = 32; off > 0; off >>= 1) {
            s += __shfl_down(s, off);
            s2 += __shfl_down(s2, off);
        }
        if (lane == 0) {
            float mu = s / 912.0f;
            float var = s2 / 912.0f - mu * mu;
            float sc = gamma[wave] * rsqrtf(var + 1e-5f);
            scaleL[wave] = sc;
            shiftL[wave] = beta[wave] - mu * sc;
        }
    }
    __syncthreads();
    if (tid < 160) {
        int b = tid / 10, o = tid % 10;
        float acc = fcb[o];
        for (int ch = 0; ch < 10; ++ch) {
            float sc = scaleL[ch], sh = shiftL[ch];
            const float* fw = fcw + o * 570 + ch * 57;
            const float* rr = r3 + ch * 912 + b * 57;
            for (int pos = 0; pos < 57; ++pos)
                acc += (rr[pos] * sc + sh) * fw[pos];
        }
        out[b * 10 + o] = acc;
    }
}

extern "C" void kernel_launch(void* const* d_in, const int* in_sizes, int n_in,
                              void* d_out, int out_size, void* d_ws, size_t ws_size,
                              hipStream_t stream) {
    const float* x   = (const float*)d_in[0];
    const float* w1r = (const float*)d_in[1];
    const float* w1i = (const float*)d_in[2];
    const float* w2r = (const float*)d_in[3];
    const float* w2i = (const float*)d_in[4];
    const float* c3w = (const float*)d_in[5];
    const float* c3b = (const float*)d_in[6];
    const float* bng = (const float*)d_in[7];
    const float* bnb = (const float*)d_in[8];
    const float* fcw = (const float*)d_in[9];
    const float* fcb = (const float*)d_in[10];
    float* ws = (float*)d_ws;
    float* out = (float*)d_out;

    hipLaunchKernelGGL(k0_consts, dim3(2279), dim3(256), 0, stream, ws);
    hipLaunchKernelGGL(k1_xh, dim3(16), dim3(256), 0, stream, x, ws,
                       (float2*)(ws + OFF_XH));
    hipLaunchKernelGGL(k2_planes, dim3(32, 32, 16), dim3(256), 0, stream, w1r, w1i, ws,
                       (float2*)(ws + OFF_XMN));
    hipLaunchKernelGGL(k3_xh2, dim3(3600), dim3(256), 0, stream, ws,
                       (const float2*)(ws + OFF_XMN), (float2*)(ws + OFF_XH2));
    hipLaunchKernelGGL(k4_U, dim3(3600), dim3(256), 0, stream, ws,
                       (const float2*)(ws + OFF_XH2), (float2*)(ws + OFF_U));
    hipLaunchKernelGGL(k5_feat, dim3(64), dim3(256), 0, stream, w2r, w2i,
                       (const float2*)(ws + OFF_U), ws + OFF_FEAT);
    hipLaunchKernelGGL(k6_head, dim3(1), dim3(640), 0, stream, ws + OFF_FEAT,
                       c3w, c3b, bng, bnb, fcw, fcb, out);
}

// Round 2
// 373.897 us; speedup vs baseline: 1.7966x; 1.7966x over previous
//
#include <hip/hip_runtime.h>
#include <math.h>

#ifndef M_PI
#define M_PI 3.14159265358979323846
#endif

// ---------------- workspace layout (float offsets) ----------------
#define OFF_D1F 0                 // [16][64][31]            31744
#define OFF_D1I 31744             // [16][32][31][31]       492032
#define OFF_D2F 523776            // D2FT: [j=32][pq=225][l=8]  57600
#define OFF_S2  581376            // [8][15][15]              1800
#define OFF_XH  583176            // float2 [16][16*31]      15872 floats
#define OFF_XMN 599048            // float2 [16][32][32][225] 7372800 floats
#define OFF_U   9815048           // float2 [16*32][8][225]  1843200 floats
#define OFF_FEAT 11658248         // [16][64]                 1024 floats

static __device__ __forceinline__ int iabs_(int v) { return v < 0 ? -v : v; }

// ---------------- K0: build constant tables (fp64) ----------------
__device__ double wig_d(int l, int m, int n, double beta, const double* LF) {
    int kmin = max(0, m - n), kmax = min(l + m, l - n);
    if (kmax < kmin) return 0.0;
    double cb = cos(0.5 * beta), sb = sin(0.5 * beta);
    double pref = 0.5 * (LF[l + m] + LF[l - m] + LF[l + n] + LF[l - n]);
    double lc = pref - LF[kmin] - LF[l + m - kmin] - LF[l - n - kmin] - LF[n - m + kmin];
    double t = exp(lc) * pow(cb, (double)(2 * l + m - n - 2 * kmin))
                       * pow(sb, (double)(n - m + 2 * kmin));
    if (kmin & 1) t = -t;
    double ratio = (sb * sb) / (cb * cb);
    double s = t;
    for (int k = kmin; k < kmax; ++k) {
        t *= -(((double)(l + m - k) * (double)(l - n - k)) /
               ((double)(k + 1) * (double)(n - m + k + 1))) * ratio;
        s += t;
    }
    return s;
}

__device__ double quadw_d(int j, int bq) {
    double beta = M_PI * (2.0 * j + 1.0) / (4.0 * bq);
    double s = 0.0;
    for (int k = 0; k < bq; ++k) s += sin((2.0 * k + 1.0) * beta) / (2.0 * k + 1.0);
    return 2.0 / bq * sin(beta) * s;
}

__global__ __launch_bounds__(256) void k0_consts(float* __restrict__ ws) {
    __shared__ double LF[64];
    int tid = threadIdx.x;
    if (tid < 64) LF[tid] = lgamma((double)tid + 1.0);
    __syncthreads();
    int gid = blockIdx.x * 256 + tid;
    if (gid >= 583176) return;

    if (gid < 31744) {                       // D1F [l][j][mh]
        int mh = gid % 31, j = (gid / 31) % 64, l = gid / (31 * 64);
        int m = mh - 15;
        double v = 0.0;
        if (iabs_(m) <= l) {
            double beta = M_PI * (2.0 * j + 1.0) / 128.0;
            v = quadw_d(j, 32) * wig_d(l, m, 0, beta, LF);
        }
        ws[OFF_D1F + gid] = (float)v;
    } else if (gid < 523776) {               // D1I [l][j][mh][nh]
        int r = gid - 31744;
        int nh = r % 31, mh = (r / 31) % 31, j = (r / 961) % 32, l = r / (961 * 32);
        int m = mh - 15, n = nh - 15;
        double v = 0.0;
        if (iabs_(m) <= l && iabs_(n) <= l) {
            double beta = M_PI * (2.0 * j + 1.0) / 64.0;
            v = (2.0 * l + 1.0) * wig_d(l, m, n, beta, LF);
        }
        ws[OFF_D1I + r] = (float)v;
    } else if (gid < 581376) {               // D2FT [j][pq][l]
        int r = gid - 523776;
        int l = r & 7;
        int pq = (r >> 3) % 225;
        int j = r / 1800;
        int mh = pq / 15, nh = pq % 15;
        int m = mh - 7, n = nh - 7;
        double v = 0.0;
        if (iabs_(m) <= l && iabs_(n) <= l) {
            double beta = M_PI * (2.0 * j + 1.0) / 64.0;
            v = quadw_d(j, 16) * wig_d(l, m, n, beta, LF);
        }
        ws[OFF_D2F + r] = (float)v;
    } else {                                 // S2 = D2I[:,0,:,:]
        int r = gid - 581376;
        int nh = r % 15, mh = (r / 15) % 15, l = r / 225;
        int m = mh - 7, n = nh - 7;
        double v = 0.0;
        if (iabs_(m) <= l && iabs_(n) <= l) {
            double beta = M_PI / 32.0;
            v = (2.0 * l + 1.0) * wig_d(l, m, n, beta, LF);
        }
        ws[OFF_S2 + r] = (float)v;
    }
}

__global__ void k_zero(float* __restrict__ p, int n) {
    int i = blockIdx.x * 256 + threadIdx.x;
    if (i < n) p[i] = 0.f;
}

// ---------------- K1: x -> xm -> xh ----------------
__global__ __launch_bounds__(256) void k1_xh(const float* __restrict__ x,
                                             const float* __restrict__ ws,
                                             float2* __restrict__ xh) {
    __shared__ float  xs[64 * 64];
    __shared__ float2 xm[64 * 31];
    __shared__ float2 cs64[64];
    int b = blockIdx.x, tid = threadIdx.x;
    for (int i = tid; i < 4096; i += 256) xs[i] = x[b * 4096 + i];
    if (tid < 64) {
        double a = 2.0 * M_PI * (double)tid / 64.0;
        cs64[tid] = make_float2((float)cos(a), (float)sin(a));
    }
    __syncthreads();
    for (int i = tid; i < 64 * 31; i += 256) {
        int mh = i % 31, j = i / 31;
        int mu = mh - 15;
        float re = 0.f, im = 0.f;
        for (int t = 0; t < 64; ++t) {
            float2 w = cs64[(mu * t) & 63];
            float xv = xs[j * 64 + t];
            re += xv * w.x;
            im -= xv * w.y;
        }
        xm[j * 31 + mh] = make_float2(re, im);
    }
    __syncthreads();
    const float* D1F = ws + OFF_D1F;
    for (int i = tid; i < 16 * 31; i += 256) {
        int mh = i % 31, l = i / 31;
        float re = 0.f, im = 0.f;
        for (int j = 0; j < 64; ++j) {
            float d = D1F[(l * 64 + j) * 31 + mh];
            float2 v = xm[j * 31 + mh];
            re += d * v.x;
            im += d * v.y;
        }
        xh[b * 496 + i] = make_float2(re, im);
    }
}

// ------- K2: per-(b,f,j) plane, radix-4 grouped DFTs, aliased LDS arena -------
__global__ __launch_bounds__(256) void k2_planes(const float* __restrict__ w1r,
                                                 const float* __restrict__ w1i,
                                                 const float* __restrict__ ws,
                                                 float2* __restrict__ xmn) {
    __shared__ char ar[16640];
    __shared__ float2 cs[32];
    float2* As = (float2*)ar;              // 496 f2    (dies after f1 stage)
    float2* Wc = (float2*)(ar + 3968);     // 496 f2    (dies after f1 stage)
    float2* f1 = (float2*)(ar + 8448);     // 31x33 f2  (dies after tt stage)
    float2* tt = (float2*)ar;              // 32x33 f2  (dies after ss stage)
    float*  ssb = (float*)(ar + 8448);     // 32x33 f   (dies after gg stage)
    float2* gg = (float2*)ar;              // 32x15 f2

    int j = blockIdx.x, f = blockIdx.y, b = blockIdx.z;
    int tid = threadIdx.x;
    const float2* xh = (const float2*)(ws + OFF_XH);
    const float*  D1I = ws + OFF_D1I;

    if (tid < 32) {
        double a = 2.0 * M_PI * (double)tid / 32.0;
        cs[tid] = make_float2((float)cos(a), (float)sin(a));
    }
    for (int i = tid; i < 496; i += 256) {
        As[i] = xh[b * 496 + i];
        int l = i / 31, nh = i % 31;
        float mask = (iabs_(nh - 15) <= l) ? 1.0f : 0.0f;
        Wc[i] = make_float2(w1r[f * 496 + i] * mask, -w1i[f * 496 + i] * mask);
    }
    __syncthreads();
    // f1[m,n] = sum_l D1I[l,j,m,n] * A[l,m] * W[l,n]   (row stride 33, pad=0)
    for (int i = tid; i < 1023; i += 256) {
        int mh = i / 33, nh = i - mh * 33;
        if (nh >= 31) { f1[i] = make_float2(0.f, 0.f); continue; }
        int l0 = iabs_(mh - 15);
        float2 acc = make_float2(0.f, 0.f);
        for (int l = l0; l < 16; ++l) {
            float d = D1I[((l * 32 + j) * 31 + mh) * 31 + nh];
            float2 a = As[l * 31 + mh];
            float2 w = Wc[l * 31 + nh];
            acc.x += d * (a.x * w.x - a.y * w.y);
            acc.y += d * (a.x * w.y + a.y * w.x);
        }
        f1[i] = acc;
    }
    __syncthreads();
    // tt[m,v] = sum_n f1[m,n] e^{+i n v th},  v = v0+8k grouped (i^{nk} signs)
    if (tid < 248) {
        int mh = tid >> 3, v0 = tid & 7;
        const float2* frow = f1 + mh * 33;
        float2 a0 = {0,0}, a1 = {0,0}, a2 = {0,0}, a3 = {0,0};
        for (int nb = 0; nb < 32; nb += 4) {
            { // n = nb-15, n mod 4 = 1
                float2 fv = frow[nb];      float2 w = cs[((nb - 15) * v0) & 31];
                float px = fv.x*w.x - fv.y*w.y, py = fv.x*w.y + fv.y*w.x;
                a0.x += px; a0.y += py;  a1.x -= py; a1.y += px;
                a2.x -= px; a2.y -= py;  a3.x += py; a3.y -= px;
            }
            { // n mod 4 = 2
                float2 fv = frow[nb + 1];  float2 w = cs[((nb - 14) * v0) & 31];
                float px = fv.x*w.x - fv.y*w.y, py = fv.x*w.y + fv.y*w.x;
                a0.x += px; a0.y += py;  a1.x -= px; a1.y -= py;
                a2.x += px; a2.y += py;  a3.x -= px; a3.y -= py;
            }
            { // n mod 4 = 3
                float2 fv = frow[nb + 2];  float2 w = cs[((nb - 13) * v0) & 31];
                float px = fv.x*w.x - fv.y*w.y, py = fv.x*w.y + fv.y*w.x;
                a0.x += px; a0.y += py;  a1.x += py; a1.y -= px;
                a2.x -= px; a2.y -= py;  a3.x -= py; a3.y += px;
            }
            { // n mod 4 = 0
                float2 fv = frow[nb + 3];  float2 w = cs[((nb - 12) * v0) & 31];
                float px = fv.x*w.x - fv.y*w.y, py = fv.x*w.y + fv.y*w.x;
                a0.x += px; a0.y += py;  a1.x += px; a1.y += py;
                a2.x += px; a2.y += py;  a3.x += px; a3.y += py;
            }
        }
        float2* trow = tt + mh * 33;
        trow[v0] = a0; trow[v0 + 8] = a1; trow[v0 + 16] = a2; trow[v0 + 24] = a3;
    } else {
        for (int v = tid - 248; v < 33; v += 8) tt[31 * 33 + v] = make_float2(0.f, 0.f);
    }
    __syncthreads();
    // ss[u,v] = relu(Re sum_m tt[m,v] e^{+i m u th}),  u = u0+8k grouped
    {
        int v = tid & 31, u0 = tid >> 5;
        float s0 = 0, s1 = 0, s2 = 0, s3 = 0;
        for (int mb = 0; mb < 32; mb += 4) {
            { // m mod 4 = 1
                float2 tv = tt[mb * 33 + v];       float2 w = cs[((mb - 15) * u0) & 31];
                float qx = tv.x*w.x - tv.y*w.y, qy = tv.x*w.y + tv.y*w.x;
                s0 += qx; s1 -= qy; s2 -= qx; s3 += qy;
            }
            { // m mod 4 = 2 (real part only needed)
                float2 tv = tt[(mb + 1) * 33 + v]; float2 w = cs[((mb - 14) * u0) & 31];
                float qx = tv.x*w.x - tv.y*w.y;
                s0 += qx; s1 -= qx; s2 += qx; s3 -= qx;
            }
            { // m mod 4 = 3
                float2 tv = tt[(mb + 2) * 33 + v]; float2 w = cs[((mb - 13) * u0) & 31];
                float qx = tv.x*w.x - tv.y*w.y, qy = tv.x*w.y + tv.y*w.x;
                s0 += qx; s1 += qy; s2 -= qx; s3 -= qy;
            }
            { // m mod 4 = 0
                float2 tv = tt[(mb + 3) * 33 + v]; float2 w = cs[((mb - 12) * u0) & 31];
                float qx = tv.x*w.x - tv.y*w.y;
                s0 += qx; s1 += qx; s2 += qx; s3 += qx;
            }
        }
        ssb[u0 * 33 + v]        = fmaxf(s0, 0.f);
        ssb[(u0 + 8) * 33 + v]  = fmaxf(s1, 0.f);
        ssb[(u0 + 16) * 33 + v] = fmaxf(s2, 0.f);
        ssb[(u0 + 24) * 33 + v] = fmaxf(s3, 0.f);
    }
    __syncthreads();
    // gg[u,q'] = sum_v ss[u,v] e^{-i q' v th};  s real => g[-q'] = conj(g[q'])
    {
        int u = tid >> 3, q = tid & 7;
        float gx = 0.f, gy = 0.f;
        for (int v = 0; v < 32; ++v) {
            float sv = ssb[u * 33 + v];
            float2 w = cs[(-(q * v)) & 31];
            gx += sv * w.x; gy += sv * w.y;
        }
        gg[u * 15 + 7 + q] = make_float2(gx, gy);
        if (q) gg[u * 15 + 7 - q] = make_float2(gx, -gy);
    }
    __syncthreads();
    // h[p',q'] = sum_u gg[u,q'] e^{-i p' u th};  h[-p',-q'] = conj(h[p',q'])
    if (tid < 113) {
        int ph, qh;
        if (tid < 105) { ph = 8 + tid / 15; qh = tid % 15; }
        else           { ph = 7; qh = 7 + (tid - 105); }
        int p = ph - 7;
        float hx = 0.f, hy = 0.f;
        for (int u = 0; u < 32; ++u) {
            float2 gv = gg[u * 15 + qh];
            float2 w = cs[(-(p * u)) & 31];
            hx += gv.x * w.x - gv.y * w.y;
            hy += gv.x * w.y + gv.y * w.x;
        }
        float2* outp = xmn + ((size_t)((b * 32 + f) * 32 + j)) * 225;
        outp[ph * 15 + qh] = make_float2(hx, hy);
        if (ph > 7 || qh > 7)
            outp[(14 - ph) * 15 + (14 - qh)] = make_float2(hx, -hy);
    }
}

// ---------- K34: fused xh2 + U, block per (b,c); xmn staged once in LDS ----------
__global__ __launch_bounds__(256) void k34_U(const float* __restrict__ ws,
                                             const float2* __restrict__ xmn,
                                             float2* __restrict__ U) {
    __shared__ char ar[64800];
    float2* xm   = (float2*)ar;            // 32x225 f2 (57600 B; dies after phase A)
    float*  S2s  = (float*)(ar + 57600);   // 1800 f
    float2* xh2s = (float2*)ar;            // 8x225 f2 (aliases xm)
    int bc = blockIdx.x, tid = threadIdx.x;

    const float4* src = (const float4*)(xmn + (size_t)bc * 7200);
    float4* dst = (float4*)ar;
    for (int i = tid; i < 3600; i += 256) dst[i] = src[i];
    for (int i = tid; i < 1800; i += 256) S2s[i] = ws[OFF_S2 + i];
    __syncthreads();

    // phase A: acc[l] = sum_j D2FT[j,pq,l] * xm[j,pq]
    float2 acc[8];
#pragma unroll
    for (int l = 0; l < 8; ++l) acc[l] = make_float2(0.f, 0.f);
    if (tid < 225) {
        const float4* dw = (const float4*)(ws + OFF_D2F);
        for (int j = 0; j < 32; ++j) {
            float2 xv = xm[j * 225 + tid];
            float4 dA = dw[(j * 225 + tid) * 2];
            float4 dB = dw[(j * 225 + tid) * 2 + 1];
            acc[0].x += dA.x * xv.x; acc[0].y += dA.x * xv.y;
            acc[1].x += dA.y * xv.x; acc[1].y += dA.y * xv.y;
            acc[2].x += dA.z * xv.x; acc[2].y += dA.z * xv.y;
            acc[3].x += dA.w * xv.x; acc[3].y += dA.w * xv.y;
            acc[4].x += dB.x * xv.x; acc[4].y += dB.x * xv.y;
            acc[5].x += dB.y * xv.x; acc[5].y += dB.y * xv.y;
            acc[6].x += dB.z * xv.x; acc[6].y += dB.z * xv.y;
            acc[7].x += dB.w * xv.x; acc[7].y += dB.w * xv.y;
        }
    }
    __syncthreads();
    if (tid < 225) {
#pragma unroll
        for (int l = 0; l < 8; ++l) xh2s[l * 225 + tid] = acc[l];
    }
    __syncthreads();

    // phase B: U[l,n,k] = sum_m S2[l,m,n] * xh2[l,m,k]
    for (int idx = tid; idx < 1800; idx += 256) {
        int l = idx / 225;
        int rem = idx - l * 225;
        int n = rem / 15, k = rem - n * 15;
        float2 a = make_float2(0.f, 0.f);
        for (int m = 0; m < 15; ++m) {
            float s = S2s[(l * 15 + m) * 15 + n];
            float2 v = xh2s[l * 225 + m * 15 + k];
            a.x += s * v.x;
            a.y += s * v.y;
        }
        U[(size_t)bc * 1800 + idx] = a;
    }
}

// ---------- K5: split-K GEMM, block per (c,l); U & w2 each read exactly once ----------
__global__ __launch_bounds__(256) void k5_feat(const float* __restrict__ w2r,
                                               const float* __restrict__ w2i,
                                               const float2* __restrict__ U,
                                               float* __restrict__ feat) {
    __shared__ char ar[57600];
    float2* Us  = (float2*)ar;             // 16x225 f2
    float2* Wsh = (float2*)(ar + 28800);   // 16x225 f2
    int c = blockIdx.x >> 3, l = blockIdx.x & 7;
    int tid = threadIdx.x;

    for (int i = tid; i < 3600; i += 256) {
        int b = i / 225, t = i - b * 225;
        Us[i] = U[(size_t)(b * 32 + c) * 1800 + l * 225 + t];
    }
    int b = tid >> 4, fl = tid & 15;
    for (int fc = 0; fc < 4; ++fc) {
        __syncthreads();
        for (int i = tid; i < 3600; i += 256) {
            int f = fc * 16 + i / 225;
            int t = i % 225;
            int n = t / 15, k = t - n * 15;
            bool valid = (iabs_(n - 7) <= l) && (iabs_(k - 7) <= l);
            int wi = ((c * 64 + f) * 8 + l) * 225 + t;
            Wsh[i] = valid ? make_float2(w2r[wi], w2i[wi]) : make_float2(0.f, 0.f);
        }
        __syncthreads();
        float accv = 0.f;
        const float2* up = Us + b * 225;
        const float2* wp = Wsh + fl * 225;
        for (int t = 0; t < 225; ++t)
            accv += up[t].x * wp[t].x + up[t].y * wp[t].y;
        atomicAdd(&feat[b * 64 + fc * 16 + fl], accv);
    }
}

// ---------------- K6: relu(feat) -> conv1d + relu + BN + fc ----------------
__global__ __launch_bounds__(640) void k6_head(const float* __restrict__ feat,
                                               const float* __restrict__ w3,
                                               const float* __restrict__ b3,
                                               const float* __restrict__ gamma,
                                               const float* __restrict__ beta,
                                               const float* __restrict__ fcw,
                                               const float* __restrict__ fcb,
                                               float* __restrict__ out) {
    __shared__ float fL[1024];
    __shared__ float w3L[80];
    __shared__ float b3L[10];
    __shared__ float r3[9120];
    __shared__ float scaleL[10], shiftL[10];
    int tid = threadIdx.x;
    for (int i = tid; i < 1024; i += 640) fL[i] = fmaxf(feat[i], 0.f);
    if (tid < 80) w3L[tid] = w3[tid];
    if (tid >= 80 && tid < 90) b3L[tid - 80] = b3[tid - 80];
    __syncthreads();
    for (int i = tid; i < 9120; i += 640) {
        int ch = i / 912;
        int r = i % 912;
        int b = r / 57, pos = r % 57;
        float acc = b3L[ch];
#pragma unroll
        for (int t = 0; t < 8; ++t) acc += fL[b * 64 + pos + t] * w3L[ch * 8 + t];
        r3[ch * 912 + r] = fmaxf(acc, 0.0f);
    }
    __syncthreads();
    int wave = tid >> 6, lane = tid & 63;
    if (wave < 10) {
        float s = 0.f, s2 = 0.f;
        for (int i = lane; i < 912; i += 64) {
            float v = r3[wave * 912 + i];
            s += v;
            s2 += v * v;
        }
        for (int off = 32; off > 0; off >>= 1) {
            s += __shfl_down(s, off);
            s2 += __shfl_down(s2, off);
        }
        if (lane == 0) {
            float mu = s / 912.0f;
            float var = s2 / 912.0f - mu * mu;
            float sc = gamma[wave] * rsqrtf(var + 1e-5f);
            scaleL[wave] = sc;
            shiftL[wave] = beta[wave] - mu * sc;
        }
    }
    __syncthreads();
    if (tid < 160) {
        int b = tid / 10, o = tid % 10;
        float acc = fcb[o];
        for (int ch = 0; ch < 10; ++ch) {
            float sc = scaleL[ch], sh = shiftL[ch];
            const float* fw = fcw + o * 570 + ch * 57;
            const float* rr = r3 + ch * 912 + b * 57;
            for (int pos = 0; pos < 57; ++pos)
                acc += (rr[pos] * sc + sh) * fw[pos];
        }
        out[b * 10 + o] = acc;
    }
}

extern "C" void kernel_launch(void* const* d_in, const int* in_sizes, int n_in,
                              void* d_out, int out_size, void* d_ws, size_t ws_size,
                              hipStream_t stream) {
    const float* x   = (const float*)d_in[0];
    const float* w1r = (const float*)d_in[1];
    const float* w1i = (const float*)d_in[2];
    const float* w2r = (const float*)d_in[3];
    const float* w2i = (const float*)d_in[4];
    const float* c3w = (const float*)d_in[5];
    const float* c3b = (const float*)d_in[6];
    const float* bng = (const float*)d_in[7];
    const float* bnb = (const float*)d_in[8];
    const float* fcw = (const float*)d_in[9];
    const float* fcb = (const float*)d_in[10];
    float* ws = (float*)d_ws;
    float* out = (float*)d_out;

    hipLaunchKernelGGL(k0_consts, dim3(2279), dim3(256), 0, stream, ws);
    hipLaunchKernelGGL(k_zero, dim3(4), dim3(256), 0, stream, ws + OFF_FEAT, 1024);
    hipLaunchKernelGGL(k1_xh, dim3(16), dim3(256), 0, stream, x, ws,
                       (float2*)(ws + OFF_XH));
    hipLaunchKernelGGL(k2_planes, dim3(32, 32, 16), dim3(256), 0, stream, w1r, w1i, ws,
                       (float2*)(ws + OFF_XMN));
    hipLaunchKernelGGL(k34_U, dim3(512), dim3(256), 0, stream, ws,
                       (const float2*)(ws + OFF_XMN), (float2*)(ws + OFF_U));
    hipLaunchKernelGGL(k5_feat, dim3(256), dim3(256), 0, stream, w2r, w2i,
                       (const float2*)(ws + OFF_U), ws + OFF_FEAT);
    hipLaunchKernelGGL(k6_head, dim3(1), dim3(640), 0, stream, ws + OFF_FEAT,
                       c3w, c3b, bng, bnb, fcw, fcb, out);
}

// Round 3
// 367.541 us; speedup vs baseline: 1.8277x; 1.0173x over previous
//
#include <hip/hip_runtime.h>
#include <math.h>

#ifndef M_PI
#define M_PI 3.14159265358979323846
#endif

// ---------------- workspace layout (float offsets) ----------------
// double tables (k0a): [0..353] doubles at float offset 0 (708 floats, pad 720)
//   LFd[64] | w0d[64]@64 | w1qd[32]@128 | cb0[64]@160 | sb0[64]@224
//   cb1[32]@288 | sb1[32]@320 | cb2s@352 | sb2s@353
#define OFF_TRIG 708              // float2 cs32[32] then cs64[64]  (192 floats)
#define OFF_D1F 900               // [16][64][31]            31744
#define OFF_D1I 32644             // [16][32][31][31]       492032
#define OFF_D2F 524676            // D2FT: [j=32][pq=225][l=8]  57600
#define OFF_S2  582276            // [8][15][15]              1800
#define OFF_XH  584076            // float2 [16][16*31]      15872 floats
#define OFF_XMN 599948            // float2 [16][32][32][225] 7372800 floats
#define OFF_U   7972748           // float2 [16*32][8][225]  1843200 floats
#define OFF_FEAT 9815948          // [16][64]                 1024 floats

static __device__ __forceinline__ int iabs_(int v) { return v < 0 ? -v : v; }

static __device__ __forceinline__ double powi_d(double x, int e) {
    double r = 1.0;
    while (e) { if (e & 1) r *= x; x *= x; e >>= 1; }
    return r;
}

// ---------------- K0a: tiny table precompute (1 block) ----------------
__global__ __launch_bounds__(256) void k0a_tables(float* __restrict__ ws) {
    double* T = (double*)ws;
    int t = threadIdx.x;
    __shared__ double lg[64];
    if (t < 64) lg[t] = (t == 0) ? 0.0 : log((double)t);
    __syncthreads();
    if (t == 0) {
        double s = 0.0;
        for (int i = 0; i < 64; ++i) { s += lg[i]; T[i] = s; }   // LF[i]=log(i!)
    }
    if (t < 64) {                       // w0 quad weights (B0=32) + half-angle trig
        double beta = M_PI * (2.0 * t + 1.0) / 128.0;
        double s = 0.0;
        for (int k = 0; k < 32; ++k) s += sin((2.0 * k + 1.0) * beta) / (2.0 * k + 1.0);
        T[64 + t] = 2.0 / 32.0 * sin(beta) * s;
        T[160 + t] = cos(0.5 * beta);
        T[224 + t] = sin(0.5 * beta);
    }
    if (t >= 64 && t < 96) {            // w1q quad weights (B1=16) + half-angle trig
        int j = t - 64;
        double beta = M_PI * (2.0 * j + 1.0) / 64.0;
        double s = 0.0;
        for (int k = 0; k < 16; ++k) s += sin((2.0 * k + 1.0) * beta) / (2.0 * k + 1.0);
        T[128 + j] = 2.0 / 16.0 * sin(beta) * s;
        T[288 + j] = cos(0.5 * beta);
        T[320 + j] = sin(0.5 * beta);
    }
    if (t == 96) {                      // beta2[0] = pi/32 half-angle
        T[352] = cos(M_PI / 64.0);
        T[353] = sin(M_PI / 64.0);
    }
    float2* F = (float2*)(ws + OFF_TRIG);
    if (t < 32) {
        double a = 2.0 * M_PI * (double)t / 32.0;
        F[t] = make_float2((float)cos(a), (float)sin(a));
    }
    if (t >= 128 && t < 192) {
        int i = t - 128;
        double a = 2.0 * M_PI * (double)i / 64.0;
        F[32 + i] = make_float2((float)cos(a), (float)sin(a));
    }
}

// ---------------- K0: build Wigner constant tables (fp64, no libcalls but exp) ----------------
__device__ double wig_fast(int l, int m, int n, double cb, double sb, const double* LF) {
    int kmin = max(0, m - n), kmax = min(l + m, l - n);
    if (kmax < kmin) return 0.0;
    double lc = 0.5 * (LF[l + m] + LF[l - m] + LF[l + n] + LF[l - n])
              - LF[kmin] - LF[l + m - kmin] - LF[l - n - kmin] - LF[n - m + kmin];
    double t = exp(lc) * powi_d(cb, 2 * l + m - n - 2 * kmin)
                       * powi_d(sb, n - m + 2 * kmin);
    if (kmin & 1) t = -t;
    double ratio = (sb * sb) / (cb * cb);
    double s = t;
    for (int k = kmin; k < kmax; ++k) {
        t *= -(((double)(l + m - k) * (double)(l - n - k)) /
               ((double)(k + 1) * (double)(n - m + k + 1))) * ratio;
        s += t;
    }
    return s;
}

__global__ __launch_bounds__(256) void k0_consts(float* __restrict__ ws) {
    const double* T = (const double*)ws;
    __shared__ double LF[64];
    int tid = threadIdx.x;
    if (tid < 64) LF[tid] = T[tid];
    __syncthreads();
    int gid = blockIdx.x * 256 + tid;
    if (gid >= 583176) return;

    if (gid < 31744) {                       // D1F [l][j][mh]
        int mh = gid % 31, j = (gid / 31) % 64, l = gid / (31 * 64);
        int m = mh - 15;
        double v = 0.0;
        if (iabs_(m) <= l)
            v = T[64 + j] * wig_fast(l, m, 0, T[160 + j], T[224 + j], LF);
        ws[OFF_D1F + gid] = (float)v;
    } else if (gid < 523776) {               // D1I [l][j][mh][nh]
        int r = gid - 31744;
        int nh = r % 31, mh = (r / 31) % 31, j = (r / 961) % 32, l = r / (961 * 32);
        int m = mh - 15, n = nh - 15;
        double v = 0.0;
        if (iabs_(m) <= l && iabs_(n) <= l)
            v = (2.0 * l + 1.0) * wig_fast(l, m, n, T[288 + j], T[320 + j], LF);
        ws[OFF_D1I + r] = (float)v;
    } else if (gid < 581376) {               // D2FT [j][pq][l]
        int r = gid - 523776;
        int l = r & 7;
        int pq = (r >> 3) % 225;
        int j = r / 1800;
        int mh = pq / 15, nh = pq % 15;
        int m = mh - 7, n = nh - 7;
        double v = 0.0;
        if (iabs_(m) <= l && iabs_(n) <= l)
            v = T[128 + j] * wig_fast(l, m, n, T[288 + j], T[320 + j], LF);
        ws[OFF_D2F + r] = (float)v;
    } else {                                 // S2 = D2I[:,0,:,:]
        int r = gid - 581376;
        int nh = r % 15, mh = (r / 15) % 15, l = r / 225;
        int m = mh - 7, n = nh - 7;
        double v = 0.0;
        if (iabs_(m) <= l && iabs_(n) <= l)
            v = (2.0 * l + 1.0) * wig_fast(l, m, n, T[352], T[353], LF);
        ws[OFF_S2 + r] = (float)v;
    }
}

__global__ void k_zero(float* __restrict__ p, int n) {
    int i = blockIdx.x * 256 + threadIdx.x;
    if (i < n) p[i] = 0.f;
}

// ---------------- K1: x -> xm -> xh  (split over mh chunks for parallelism) ----------------
__global__ __launch_bounds__(256) void k1_xh(const float* __restrict__ x,
                                             const float* __restrict__ ws,
                                             float2* __restrict__ xh) {
    __shared__ float  xs[64 * 64];
    __shared__ float2 xm[64 * 8];
    __shared__ float2 cs64[64];
    int c = blockIdx.x, b = blockIdx.y, tid = threadIdx.x;
    int mh0 = c * 8;
    int cnt = min(8, 31 - mh0);
    for (int i = tid; i < 4096; i += 256) xs[i] = x[b * 4096 + i];
    if (tid < 64) cs64[tid] = ((const float2*)(ws + OFF_TRIG))[32 + tid];
    __syncthreads();
    for (int i = tid; i < 512; i += 256) {
        int j = i >> 3, mi = i & 7;
        if (mi < cnt) {
            int mu = mh0 + mi - 15;
            float re = 0.f, im = 0.f;
            for (int t = 0; t < 64; ++t) {
                float2 w = cs64[(mu * t) & 63];
                float xv = xs[j * 64 + t];
                re += xv * w.x;
                im -= xv * w.y;
            }
            xm[i] = make_float2(re, im);
        }
    }
    __syncthreads();
    const float* D1F = ws + OFF_D1F;
    if (tid < 128) {
        int l = tid >> 3, mi = tid & 7;
        if (mi < cnt) {
            int mh = mh0 + mi;
            float re = 0.f, im = 0.f;
            for (int j = 0; j < 64; ++j) {
                float d = D1F[(l * 64 + j) * 31 + mh];
                float2 v = xm[j * 8 + mi];
                re += d * v.x;
                im += d * v.y;
            }
            xh[b * 496 + l * 31 + mh] = make_float2(re, im);
        }
    }
}

// ------- K2: per-(b,f,j) plane, radix-4 grouped DFTs, aliased LDS arena -------
__global__ __launch_bounds__(256) void k2_planes(const float* __restrict__ w1r,
                                                 const float* __restrict__ w1i,
                                                 const float* __restrict__ ws,
                                                 float2* __restrict__ xmn) {
    __shared__ char ar[16640];
    __shared__ float2 cs[32];
    float2* As = (float2*)ar;              // 496 f2    (dies after f1 stage)
    float2* Wc = (float2*)(ar + 3968);     // 496 f2    (dies after f1 stage)
    float2* f1 = (float2*)(ar + 8448);     // 31x33 f2  (dies after tt stage)
    float2* tt = (float2*)ar;              // 32x33 f2  (dies after ss stage)
    float*  ssb = (float*)(ar + 8448);     // 32x33 f   (dies after gg stage)
    float2* gg = (float2*)ar;              // 32x15 f2

    int j = blockIdx.x, f = blockIdx.y, b = blockIdx.z;
    int tid = threadIdx.x;
    const float2* xh = (const float2*)(ws + OFF_XH);
    const float*  D1I = ws + OFF_D1I;

    if (tid < 32) cs[tid] = ((const float2*)(ws + OFF_TRIG))[tid];
    for (int i = tid; i < 496; i += 256) {
        As[i] = xh[b * 496 + i];
        int l = i / 31, nh = i % 31;
        float mask = (iabs_(nh - 15) <= l) ? 1.0f : 0.0f;
        Wc[i] = make_float2(w1r[f * 496 + i] * mask, -w1i[f * 496 + i] * mask);
    }
    __syncthreads();
    // f1[m,n] = sum_l D1I[l,j,m,n] * A[l,m] * W[l,n]   (row stride 33, pad=0)
    // terms with l < max(|m|,|n|) are exactly zero (A and W masked) -> skip
    for (int i = tid; i < 1023; i += 256) {
        int mh = i / 33, nh = i - mh * 33;
        if (nh >= 31) { f1[i] = make_float2(0.f, 0.f); continue; }
        int l0 = max(iabs_(mh - 15), iabs_(nh - 15));
        float2 acc = make_float2(0.f, 0.f);
        for (int l = l0; l < 16; ++l) {
            float d = D1I[((l * 32 + j) * 31 + mh) * 31 + nh];
            float2 a = As[l * 31 + mh];
            float2 w = Wc[l * 31 + nh];
            acc.x += d * (a.x * w.x - a.y * w.y);
            acc.y += d * (a.x * w.y + a.y * w.x);
        }
        f1[i] = acc;
    }
    __syncthreads();
    // tt[m,v] = sum_n f1[m,n] e^{+i n v th},  v = v0+8k grouped (i^{nk} signs)
    if (tid < 248) {
        int mh = tid >> 3, v0 = tid & 7;
        const float2* frow = f1 + mh * 33;
        float2 a0 = {0,0}, a1 = {0,0}, a2 = {0,0}, a3 = {0,0};
        for (int nb = 0; nb < 32; nb += 4) {
            { // n = nb-15, n mod 4 = 1
                float2 fv = frow[nb];      float2 w = cs[((nb - 15) * v0) & 31];
                float px = fv.x*w.x - fv.y*w.y, py = fv.x*w.y + fv.y*w.x;
                a0.x += px; a0.y += py;  a1.x -= py; a1.y += px;
                a2.x -= px; a2.y -= py;  a3.x += py; a3.y -= px;
            }
            { // n mod 4 = 2
                float2 fv = frow[nb + 1];  float2 w = cs[((nb - 14) * v0) & 31];
                float px = fv.x*w.x - fv.y*w.y, py = fv.x*w.y + fv.y*w.x;
                a0.x += px; a0.y += py;  a1.x -= px; a1.y -= py;
                a2.x += px; a2.y += py;  a3.x -= px; a3.y -= py;
            }
            { // n mod 4 = 3
                float2 fv = frow[nb + 2];  float2 w = cs[((nb - 13) * v0) & 31];
                float px = fv.x*w.x - fv.y*w.y, py = fv.x*w.y + fv.y*w.x;
                a0.x += px; a0.y += py;  a1.x += py; a1.y -= px;
                a2.x -= px; a2.y -= py;  a3.x -= py; a3.y += px;
            }
            { // n mod 4 = 0
                float2 fv = frow[nb + 3];  float2 w = cs[((nb - 12) * v0) & 31];
                float px = fv.x*w.x - fv.y*w.y, py = fv.x*w.y + fv.y*w.x;
                a0.x += px; a0.y += py;  a1.x += px; a1.y += py;
                a2.x += px; a2.y += py;  a3.x += px; a3.y += py;
            }
        }
        float2* trow = tt + mh * 33;
        trow[v0] = a0; trow[v0 + 8] = a1; trow[v0 + 16] = a2; trow[v0 + 24] = a3;
    } else {
        for (int v = tid - 248; v < 33; v += 8) tt[31 * 33 + v] = make_float2(0.f, 0.f);
    }
    __syncthreads();
    // ss[u,v] = relu(Re sum_m tt[m,v] e^{+i m u th}),  u = u0+8k grouped
    {
        int v = tid & 31, u0 = tid >> 5;
        float s0 = 0, s1 = 0, s2 = 0, s3 = 0;
        for (int mb = 0; mb < 32; mb += 4) {
            { // m mod 4 = 1
                float2 tv = tt[mb * 33 + v];       float2 w = cs[((mb - 15) * u0) & 31];
                float qx = tv.x*w.x - tv.y*w.y, qy = tv.x*w.y + tv.y*w.x;
                s0 += qx; s1 -= qy; s2 -= qx; s3 += qy;
            }
            { // m mod 4 = 2 (real part only needed)
                float2 tv = tt[(mb + 1) * 33 + v]; float2 w = cs[((mb - 14) * u0) & 31];
                float qx = tv.x*w.x - tv.y*w.y;
                s0 += qx; s1 -= qx; s2 += qx; s3 -= qx;
            }
            { // m mod 4 = 3
                float2 tv = tt[(mb + 2) * 33 + v]; float2 w = cs[((mb - 13) * u0) & 31];
                float qx = tv.x*w.x - tv.y*w.y, qy = tv.x*w.y + tv.y*w.x;
                s0 += qx; s1 += qy; s2 -= qx; s3 -= qy;
            }
            { // m mod 4 = 0
                float2 tv = tt[(mb + 3) * 33 + v]; float2 w = cs[((mb - 12) * u0) & 31];
                float qx = tv.x*w.x - tv.y*w.y;
                s0 += qx; s1 += qx; s2 += qx; s3 += qx;
            }
        }
        ssb[u0 * 33 + v]        = fmaxf(s0, 0.f);
        ssb[(u0 + 8) * 33 + v]  = fmaxf(s1, 0.f);
        ssb[(u0 + 16) * 33 + v] = fmaxf(s2, 0.f);
        ssb[(u0 + 24) * 33 + v] = fmaxf(s3, 0.f);
    }
    __syncthreads();
    // gg[u,q'] = sum_v ss[u,v] e^{-i q' v th};  s real => g[-q'] = conj(g[q'])
    {
        int u = tid >> 3, q = tid & 7;
        float gx = 0.f, gy = 0.f;
        for (int v = 0; v < 32; ++v) {
            float sv = ssb[u * 33 + v];
            float2 w = cs[(-(q * v)) & 31];
            gx += sv * w.x; gy += sv * w.y;
        }
        gg[u * 15 + 7 + q] = make_float2(gx, gy);
        if (q) gg[u * 15 + 7 - q] = make_float2(gx, -gy);
    }
    __syncthreads();
    // h[p',q'] = sum_u gg[u,q'] e^{-i p' u th};  h[-p',-q'] = conj(h[p',q'])
    if (tid < 113) {
        int ph, qh;
        if (tid < 105) { ph = 8 + tid / 15; qh = tid % 15; }
        else           { ph = 7; qh = 7 + (tid - 105); }
        int p = ph - 7;
        float hx = 0.f, hy = 0.f;
        for (int u = 0; u < 32; ++u) {
            float2 gv = gg[u * 15 + qh];
            float2 w = cs[(-(p * u)) & 31];
            hx += gv.x * w.x - gv.y * w.y;
            hy += gv.x * w.y + gv.y * w.x;
        }
        float2* outp = xmn + ((size_t)((b * 32 + f) * 32 + j)) * 225;
        outp[ph * 15 + qh] = make_float2(hx, hy);
        if (ph > 7 || qh > 7)
            outp[(14 - ph) * 15 + (14 - qh)] = make_float2(hx, -hy);
    }
}

// ---------- K34: fused xh2 + U, block per (b,c); xmn staged once in LDS ----------
__global__ __launch_bounds__(256) void k34_U(const float* __restrict__ ws,
                                             const float2* __restrict__ xmn,
                                             float2* __restrict__ U) {
    __shared__ char ar[64800];
    float2* xm   = (float2*)ar;            // 32x225 f2 (57600 B; dies after phase A)
    float*  S2s  = (float*)(ar + 57600);   // 1800 f
    float2* xh2s = (float2*)ar;            // 8x225 f2 (aliases xm)
    int bc = blockIdx.x, tid = threadIdx.x;

    const float4* src = (const float4*)(xmn + (size_t)bc * 7200);
    float4* dst = (float4*)ar;
    for (int i = tid; i < 3600; i += 256) dst[i] = src[i];
    for (int i = tid; i < 1800; i += 256) S2s[i] = ws[OFF_S2 + i];
    __syncthreads();

    float2 acc[8];
#pragma unroll
    for (int l = 0; l < 8; ++l) acc[l] = make_float2(0.f, 0.f);
    if (tid < 225) {
        const float4* dw = (const float4*)(ws + OFF_D2F);
        for (int j = 0; j < 32; ++j) {
            float2 xv = xm[j * 225 + tid];
            float4 dA = dw[(j * 225 + tid) * 2];
            float4 dB = dw[(j * 225 + tid) * 2 + 1];
            acc[0].x += dA.x * xv.x; acc[0].y += dA.x * xv.y;
            acc[1].x += dA.y * xv.x; acc[1].y += dA.y * xv.y;
            acc[2].x += dA.z * xv.x; acc[2].y += dA.z * xv.y;
            acc[3].x += dA.w * xv.x; acc[3].y += dA.w * xv.y;
            acc[4].x += dB.x * xv.x; acc[4].y += dB.x * xv.y;
            acc[5].x += dB.y * xv.x; acc[5].y += dB.y * xv.y;
            acc[6].x += dB.z * xv.x; acc[6].y += dB.z * xv.y;
            acc[7].x += dB.w * xv.x; acc[7].y += dB.w * xv.y;
        }
    }
    __syncthreads();
    if (tid < 225) {
#pragma unroll
        for (int l = 0; l < 8; ++l) xh2s[l * 225 + tid] = acc[l];
    }
    __syncthreads();

    for (int idx = tid; idx < 1800; idx += 256) {
        int l = idx / 225;
        int rem = idx - l * 225;
        int n = rem / 15, k = rem - n * 15;
        float2 a = make_float2(0.f, 0.f);
        for (int m = 0; m < 15; ++m) {
            float s = S2s[(l * 15 + m) * 15 + n];
            float2 v = xh2s[l * 225 + m * 15 + k];
            a.x += s * v.x;
            a.y += s * v.y;
        }
        U[(size_t)bc * 1800 + idx] = a;
    }
}

// ---------- K5: split-K GEMM, block per (c,l); U & w2 each read exactly once ----------
__global__ __launch_bounds__(256) void k5_feat(const float* __restrict__ w2r,
                                               const float* __restrict__ w2i,
                                               const float2* __restrict__ U,
                                               float* __restrict__ feat) {
    __shared__ char ar[57600];
    float2* Us  = (float2*)ar;             // 16x225 f2
    float2* Wsh = (float2*)(ar + 28800);   // 16x225 f2
    int c = blockIdx.x >> 3, l = blockIdx.x & 7;
    int tid = threadIdx.x;

    for (int i = tid; i < 3600; i += 256) {
        int b = i / 225, t = i - b * 225;
        Us[i] = U[(size_t)(b * 32 + c) * 1800 + l * 225 + t];
    }
    int b = tid >> 4, fl = tid & 15;
    for (int fc = 0; fc < 4; ++fc) {
        __syncthreads();
        for (int i = tid; i < 3600; i += 256) {
            int f = fc * 16 + i / 225;
            int t = i % 225;
            int n = t / 15, k = t - n * 15;
            bool valid = (iabs_(n - 7) <= l) && (iabs_(k - 7) <= l);
            int wi = ((c * 64 + f) * 8 + l) * 225 + t;
            Wsh[i] = valid ? make_float2(w2r[wi], w2i[wi]) : make_float2(0.f, 0.f);
        }
        __syncthreads();
        float accv = 0.f;
        const float2* up = Us + b * 225;
        const float2* wp = Wsh + fl * 225;
        for (int t = 0; t < 225; ++t)
            accv += up[t].x * wp[t].x + up[t].y * wp[t].y;
        atomicAdd(&feat[b * 64 + fc * 16 + fl], accv);
    }
}

// ---------------- K6: relu(feat) -> conv1d + relu + BN + fc ----------------
__global__ __launch_bounds__(640) void k6_head(const float* __restrict__ feat,
                                               const float* __restrict__ w3,
                                               const float* __restrict__ b3,
                                               const float* __restrict__ gamma,
                                               const float* __restrict__ beta,
                                               const float* __restrict__ fcw,
                                               const float* __restrict__ fcb,
                                               float* __restrict__ out) {
    __shared__ float fL[1024];
    __shared__ float w3L[80];
    __shared__ float b3L[10];
    __shared__ float r3[9120];
    __shared__ float scaleL[10], shiftL[10];
    int tid = threadIdx.x;
    for (int i = tid; i < 1024; i += 640) fL[i] = fmaxf(feat[i], 0.f);
    if (tid < 80) w3L[tid] = w3[tid];
    if (tid >= 80 && tid < 90) b3L[tid - 80] = b3[tid - 80];
    __syncthreads();
    for (int i = tid; i < 9120; i += 640) {
        int ch = i / 912;
        int r = i % 912;
        int b = r / 57, pos = r % 57;
        float acc = b3L[ch];
#pragma unroll
        for (int t = 0; t < 8; ++t) acc += fL[b * 64 + pos + t] * w3L[ch * 8 + t];
        r3[ch * 912 + r] = fmaxf(acc, 0.0f);
    }
    __syncthreads();
    int wave = tid >> 6, lane = tid & 63;
    if (wave < 10) {
        float s = 0.f, s2 = 0.f;
        for (int i = lane; i < 912; i += 64) {
            float v = r3[wave * 912 + i];
            s += v;
            s2 += v * v;
        }
        for (int off = 32; off > 0; off >>= 1) {
            s += __shfl_down(s, off);
            s2 += __shfl_down(s2, off);
        }
        if (lane == 0) {
            float mu = s / 912.0f;
            float var = s2 / 912.0f - mu * mu;
            float sc = gamma[wave] * rsqrtf(var + 1e-5f);
            scaleL[wave] = sc;
            shiftL[wave] = beta[wave] - mu * sc;
        }
    }
    __syncthreads();
    if (tid < 160) {
        int b = tid / 10, o = tid % 10;
        float acc = fcb[o];
        for (int ch = 0; ch < 10; ++ch) {
            float sc = scaleL[ch], sh = shiftL[ch];
            const float* fw = fcw + o * 570 + ch * 57;
            const float* rr = r3 + ch * 912 + b * 57;
            for (int pos = 0; pos < 57; ++pos)
                acc += (rr[pos] * sc + sh) * fw[pos];
        }
        out[b * 10 + o] = acc;
    }
}

extern "C" void kernel_launch(void* const* d_in, const int* in_sizes, int n_in,
                              void* d_out, int out_size, void* d_ws, size_t ws_size,
                              hipStream_t stream) {
    const float* x   = (const float*)d_in[0];
    const float* w1r = (const float*)d_in[1];
    const float* w1i = (const float*)d_in[2];
    const float* w2r = (const float*)d_in[3];
    const float* w2i = (const float*)d_in[4];
    const float* c3w = (const float*)d_in[5];
    const float* c3b = (const float*)d_in[6];
    const float* bng = (const float*)d_in[7];
    const float* bnb = (const float*)d_in[8];
    const float* fcw = (const float*)d_in[9];
    const float* fcb = (const float*)d_in[10];
    float* ws = (float*)d_ws;
    float* out = (float*)d_out;

    hipLaunchKernelGGL(k0a_tables, dim3(1), dim3(256), 0, stream, ws);
    hipLaunchKernelGGL(k0_consts, dim3(2279), dim3(256), 0, stream, ws);
    hipLaunchKernelGGL(k_zero, dim3(4), dim3(256), 0, stream, ws + OFF_FEAT, 1024);
    hipLaunchKernelGGL(k1_xh, dim3(4, 16), dim3(256), 0, stream, x, ws,
                       (float2*)(ws + OFF_XH));
    hipLaunchKernelGGL(k2_planes, dim3(32, 32, 16), dim3(256), 0, stream, w1r, w1i, ws,
                       (float2*)(ws + OFF_XMN));
    hipLaunchKernelGGL(k34_U, dim3(512), dim3(256), 0, stream, ws,
                       (const float2*)(ws + OFF_XMN), (float2*)(ws + OFF_U));
    hipLaunchKernelGGL(k5_feat, dim3(256), dim3(256), 0, stream, w2r, w2i,
                       (const float2*)(ws + OFF_U), ws + OFF_FEAT);
    hipLaunchKernelGGL(k6_head, dim3(1), dim3(640), 0, stream, ws + OFF_FEAT,
                       c3w, c3b, bng, bnb, fcw, fcb, out);
}

// Round 4
// 362.911 us; speedup vs baseline: 1.8510x; 1.0128x over previous
//
#include <hip/hip_runtime.h>
#include <math.h>

#ifndef M_PI
#define M_PI 3.14159265358979323846
#endif

// ---------------- workspace layout (float offsets) ----------------
// double tables (k0a): [0..353] doubles at float offset 0 (708 floats, pad 720)
//   LFd[64] | w0d[64]@64 | w1qd[32]@128 | cb0[64]@160 | sb0[64]@224
//   cb1[32]@288 | sb1[32]@320 | cb2s@352 | sb2s@353
#define OFF_TRIG 708              // float2 cs32[32] then cs64[64]  (192 floats)
#define OFF_D1F 900               // [16][64][31]                 31744
#define OFF_D1I 32644             // D1IT: [j=32][mh=31][l=16][nh=32]  507904
#define OFF_D2F 540548            // D2FT: [j=32][pq=225][l=8]    57600
#define OFF_S2  598148            // [8][15][15]                   1800
#define OFF_XH  599948            // float2 [16][16*31]           15872 floats
#define OFF_XMN 615820            // float2 [16][32][32][225]   7372800 floats
#define OFF_U   7988620           // float2 [16*32][8][225]     1843200 floats
#define OFF_FEAT 9831820          // [16][64]                      1024 floats

static __device__ __forceinline__ int iabs_(int v) { return v < 0 ? -v : v; }

static __device__ __forceinline__ double powi_d(double x, int e) {
    double r = 1.0;
    while (e) { if (e & 1) r *= x; x *= x; e >>= 1; }
    return r;
}

// ---------------- K0a: tiny table precompute (1 block) + feat zero ----------------
__global__ __launch_bounds__(256) void k0a_tables(float* __restrict__ ws) {
    double* T = (double*)ws;
    int t = threadIdx.x;
    __shared__ double lg[64];
    if (t < 64) lg[t] = (t == 0) ? 0.0 : log((double)t);
    __syncthreads();
    if (t == 0) {
        double s = 0.0;
        for (int i = 0; i < 64; ++i) { s += lg[i]; T[i] = s; }   // LF[i]=log(i!)
    }
    if (t < 64) {                       // w0 quad weights (B0=32) + half-angle trig
        double beta = M_PI * (2.0 * t + 1.0) / 128.0;
        double s = 0.0;
        for (int k = 0; k < 32; ++k) s += sin((2.0 * k + 1.0) * beta) / (2.0 * k + 1.0);
        T[64 + t] = 2.0 / 32.0 * sin(beta) * s;
        T[160 + t] = cos(0.5 * beta);
        T[224 + t] = sin(0.5 * beta);
    }
    if (t >= 64 && t < 96) {            // w1q quad weights (B1=16) + half-angle trig
        int j = t - 64;
        double beta = M_PI * (2.0 * j + 1.0) / 64.0;
        double s = 0.0;
        for (int k = 0; k < 16; ++k) s += sin((2.0 * k + 1.0) * beta) / (2.0 * k + 1.0);
        T[128 + j] = 2.0 / 16.0 * sin(beta) * s;
        T[288 + j] = cos(0.5 * beta);
        T[320 + j] = sin(0.5 * beta);
    }
    if (t == 96) {                      // beta2[0] = pi/32 half-angle
        T[352] = cos(M_PI / 64.0);
        T[353] = sin(M_PI / 64.0);
    }
    float2* F = (float2*)(ws + OFF_TRIG);
    if (t < 32) {
        double a = 2.0 * M_PI * (double)t / 32.0;
        F[t] = make_float2((float)cos(a), (float)sin(a));
    }
    if (t >= 128 && t < 192) {
        int i = t - 128;
        double a = 2.0 * M_PI * (double)i / 64.0;
        F[32 + i] = make_float2((float)cos(a), (float)sin(a));
    }
    for (int i = t; i < 1024; i += 256) ws[OFF_FEAT + i] = 0.f;   // feat zero
}

// ---------------- K0: build Wigner constant tables ----------------
__device__ double wig_fast(int l, int m, int n, double cb, double sb, const double* LF) {
    int kmin = max(0, m - n), kmax = min(l + m, l - n);
    if (kmax < kmin) return 0.0;
    double lc = 0.5 * (LF[l + m] + LF[l - m] + LF[l + n] + LF[l - n])
              - LF[kmin] - LF[l + m - kmin] - LF[l - n - kmin] - LF[n - m + kmin];
    double t = exp(lc) * powi_d(cb, 2 * l + m - n - 2 * kmin)
                       * powi_d(sb, n - m + 2 * kmin);
    if (kmin & 1) t = -t;
    double ratio = (sb * sb) / (cb * cb);
    double s = t;
    for (int k = kmin; k < kmax; ++k) {
        t *= -(((double)(l + m - k) * (double)(l - n - k)) /
               ((double)(k + 1) * (double)(n - m + k + 1))) * ratio;
        s += t;
    }
    return s;
}

__global__ __launch_bounds__(256) void k0_consts(float* __restrict__ ws) {
    const double* T = (const double*)ws;
    __shared__ double LF[64];
    int tid = threadIdx.x;
    if (tid < 64) LF[tid] = T[tid];
    __syncthreads();
    int gid = blockIdx.x * 256 + tid;
    if (gid >= 599048) return;

    if (gid < 31744) {                       // D1F [l][j][mh]
        int mh = gid % 31, j = (gid / 31) % 64, l = gid / (31 * 64);
        int m = mh - 15;
        double v = 0.0;
        if (iabs_(m) <= l)
            v = T[64 + j] * wig_fast(l, m, 0, T[160 + j], T[224 + j], LF);
        ws[OFF_D1F + gid] = (float)v;
    } else if (gid < 539648) {               // D1IT [j][mh][l][nh32]
        int r = gid - 31744;
        int nh = r & 31;
        int l  = (r >> 5) & 15;
        int mh = (r >> 9) % 31;
        int j  = r / (512 * 31);
        int m = mh - 15, n = nh - 15;
        double v = 0.0;
        if (nh < 31 && iabs_(m) <= l && iabs_(n) <= l)
            v = (2.0 * l + 1.0) * wig_fast(l, m, n, T[288 + j], T[320 + j], LF);
        ws[OFF_D1I + r] = (float)v;
    } else if (gid < 597248) {               // D2FT [j][pq][l]
        int r = gid - 539648;
        int l = r & 7;
        int pq = (r >> 3) % 225;
        int j = r / 1800;
        int mh = pq / 15, nh = pq % 15;
        int m = mh - 7, n = nh - 7;
        double v = 0.0;
        if (iabs_(m) <= l && iabs_(n) <= l)
            v = T[128 + j] * wig_fast(l, m, n, T[288 + j], T[320 + j], LF);
        ws[OFF_D2F + r] = (float)v;
    } else {                                 // S2 = D2I[:,0,:,:]
        int r = gid - 597248;
        int nh = r % 15, mh = (r / 15) % 15, l = r / 225;
        int m = mh - 7, n = nh - 7;
        double v = 0.0;
        if (iabs_(m) <= l && iabs_(n) <= l)
            v = (2.0 * l + 1.0) * wig_fast(l, m, n, T[352], T[353], LF);
        ws[OFF_S2 + r] = (float)v;
    }
}

// ---------------- K1: x -> xm -> xh ----------------
__global__ __launch_bounds__(256) void k1_xh(const float* __restrict__ x,
                                             const float* __restrict__ ws,
                                             float2* __restrict__ xh) {
    __shared__ float  xs[64 * 64];
    __shared__ float2 xm[64 * 8];
    __shared__ float2 cs64[64];
    int c = blockIdx.x, b = blockIdx.y, tid = threadIdx.x;
    int mh0 = c * 8;
    int cnt = min(8, 31 - mh0);
    for (int i = tid; i < 4096; i += 256) xs[i] = x[b * 4096 + i];
    if (tid < 64) cs64[tid] = ((const float2*)(ws + OFF_TRIG))[32 + tid];
    __syncthreads();
    for (int i = tid; i < 512; i += 256) {
        int j = i >> 3, mi = i & 7;
        if (mi < cnt) {
            int mu = mh0 + mi - 15;
            float re = 0.f, im = 0.f;
            for (int t = 0; t < 64; ++t) {
                float2 w = cs64[(mu * t) & 63];
                float xv = xs[j * 64 + t];
                re += xv * w.x;
                im -= xv * w.y;
            }
            xm[i] = make_float2(re, im);
        }
    }
    __syncthreads();
    const float* D1F = ws + OFF_D1F;
    if (tid < 128) {
        int l = tid >> 3, mi = tid & 7;
        if (mi < cnt) {
            int mh = mh0 + mi;
            float re = 0.f, im = 0.f;
            for (int j = 0; j < 64; ++j) {
                float d = D1F[(l * 64 + j) * 31 + mh];
                float2 v = xm[j * 8 + mi];
                re += d * v.x;
                im += d * v.y;
            }
            xh[b * 496 + l * 31 + mh] = make_float2(re, im);
        }
    }
}

// ------- K2: per-(b,f,j) plane; register-tiled f1, radix-4 DFTs, aliased arena -------
__global__ __launch_bounds__(256) void k2_planes(const float* __restrict__ w1r,
                                                 const float* __restrict__ w1i,
                                                 const float* __restrict__ ws,
                                                 float2* __restrict__ xmn) {
    __shared__ char ar[16896];
    __shared__ float2 cs[32];
    float2* As  = (float2*)ar;             // 496 f2 [l*31+mh]          (dies after f1)
    float2* Wc  = (float2*)(ar + 4096);    // 16x32 f2 [l*32+nh] masked (dies after f1)
    float2* f1  = (float2*)(ar + 8448);    // 31 rows, stride 34 f2     (dies after tt)
    float2* tt  = (float2*)ar;             // 32x33 f2                  (dies after ss)
    float*  ssb = (float*)(ar + 8448);     // 32x33 f                   (dies after gg)
    float2* gg  = (float2*)ar;             // 32x15 f2

    int j = blockIdx.x, f = blockIdx.y, b = blockIdx.z;
    int tid = threadIdx.x;
    const float2* xh = (const float2*)(ws + OFF_XH);

    if (tid < 32) cs[tid] = ((const float2*)(ws + OFF_TRIG))[tid];
    for (int i = tid; i < 496; i += 256) As[i] = xh[b * 496 + i];
    for (int i = tid; i < 512; i += 256) {
        int l = i >> 5, nh = i & 31;
        float mask = (nh < 31 && iabs_(nh - 15) <= l) ? 1.0f : 0.0f;
        int src = f * 496 + l * 31 + min(nh, 30);
        Wc[i] = make_float2(w1r[src] * mask, -w1i[src] * mask);
    }
    __syncthreads();
    // f1[m, nh0..nh0+3] = sum_l D1IT[j,m,l,nh] * A[l,m] * W[l,nh]
    {
        int mrow = tid >> 3;
        int nh0 = (tid & 7) * 4;
        if (mrow < 31) {
            int l0 = iabs_(mrow - 15);
            float2 a0 = {0,0}, a1 = {0,0}, a2 = {0,0}, a3 = {0,0};
            const float* Dbase = ws + OFF_D1I + ((j * 31 + mrow) * 16) * 32 + nh0;
            for (int l = l0; l < 16; ++l) {
                float2 a = As[l * 31 + mrow];
                float4 w01 = *(const float4*)(Wc + l * 32 + nh0);
                float4 w23 = *(const float4*)(Wc + l * 32 + nh0 + 2);
                float4 d = *(const float4*)(Dbase + l * 32);
                float t;
                t = a.x*w01.x - a.y*w01.y; a0.x += d.x*t;
                t = a.x*w01.y + a.y*w01.x; a0.y += d.x*t;
                t = a.x*w01.z - a.y*w01.w; a1.x += d.y*t;
                t = a.x*w01.w + a.y*w01.z; a1.y += d.y*t;
                t = a.x*w23.x - a.y*w23.y; a2.x += d.z*t;
                t = a.x*w23.y + a.y*w23.x; a2.y += d.z*t;
                t = a.x*w23.z - a.y*w23.w; a3.x += d.w*t;
                t = a.x*w23.w + a.y*w23.z; a3.y += d.w*t;
            }
            float2* fr = f1 + mrow * 34 + nh0;
            fr[0] = a0; fr[1] = a1; fr[2] = a2; fr[3] = a3;
        }
    }
    __syncthreads();
    // tt[m,v] = sum_n f1[m,n] e^{+i n v th},  v = v0+8k grouped (i^{nk} signs)
    if (tid < 248) {
        int mh = tid >> 3, v0 = tid & 7;
        const float2* frow = f1 + mh * 34;
        float2 a0 = {0,0}, a1 = {0,0}, a2 = {0,0}, a3 = {0,0};
        for (int nb = 0; nb < 32; nb += 4) {
            float4 q01 = *(const float4*)(frow + nb);
            float4 q23 = *(const float4*)(frow + nb + 2);
            { // n = nb-15, n mod 4 = 1
                float2 w = cs[((nb - 15) * v0) & 31];
                float px = q01.x*w.x - q01.y*w.y, py = q01.x*w.y + q01.y*w.x;
                a0.x += px; a0.y += py;  a1.x -= py; a1.y += px;
                a2.x -= px; a2.y -= py;  a3.x += py; a3.y -= px;
            }
            { // n mod 4 = 2
                float2 w = cs[((nb - 14) * v0) & 31];
                float px = q01.z*w.x - q01.w*w.y, py = q01.z*w.y + q01.w*w.x;
                a0.x += px; a0.y += py;  a1.x -= px; a1.y -= py;
                a2.x += px; a2.y += py;  a3.x -= px; a3.y -= py;
            }
            { // n mod 4 = 3
                float2 w = cs[((nb - 13) * v0) & 31];
                float px = q23.x*w.x - q23.y*w.y, py = q23.x*w.y + q23.y*w.x;
                a0.x += px; a0.y += py;  a1.x += py; a1.y -= px;
                a2.x -= px; a2.y -= py;  a3.x -= py; a3.y += px;
            }
            { // n mod 4 = 0
                float2 w = cs[((nb - 12) * v0) & 31];
                float px = q23.z*w.x - q23.w*w.y, py = q23.z*w.y + q23.w*w.x;
                a0.x += px; a0.y += py;  a1.x += px; a1.y += py;
                a2.x += px; a2.y += py;  a3.x += px; a3.y += py;
            }
        }
        float2* trow = tt + mh * 33;
        trow[v0] = a0; trow[v0 + 8] = a1; trow[v0 + 16] = a2; trow[v0 + 24] = a3;
    } else {
        for (int v = tid - 248; v < 33; v += 8) tt[31 * 33 + v] = make_float2(0.f, 0.f);
    }
    __syncthreads();
    // ss[u,v] = relu(Re sum_m tt[m,v] e^{+i m u th}),  u = u0+8k grouped
    {
        int v = tid & 31, u0 = tid >> 5;
        float s0 = 0, s1 = 0, s2 = 0, s3 = 0;
        for (int mb = 0; mb < 32; mb += 4) {
            { // m mod 4 = 1
                float2 tv = tt[mb * 33 + v];       float2 w = cs[((mb - 15) * u0) & 31];
                float qx = tv.x*w.x - tv.y*w.y, qy = tv.x*w.y + tv.y*w.x;
                s0 += qx; s1 -= qy; s2 -= qx; s3 += qy;
            }
            { // m mod 4 = 2 (real part only)
                float2 tv = tt[(mb + 1) * 33 + v]; float2 w = cs[((mb - 14) * u0) & 31];
                float qx = tv.x*w.x - tv.y*w.y;
                s0 += qx; s1 -= qx; s2 += qx; s3 -= qx;
            }
            { // m mod 4 = 3
                float2 tv = tt[(mb + 2) * 33 + v]; float2 w = cs[((mb - 13) * u0) & 31];
                float qx = tv.x*w.x - tv.y*w.y, qy = tv.x*w.y + tv.y*w.x;
                s0 += qx; s1 += qy; s2 -= qx; s3 -= qy;
            }
            { // m mod 4 = 0
                float2 tv = tt[(mb + 3) * 33 + v]; float2 w = cs[((mb - 12) * u0) & 31];
                float qx = tv.x*w.x - tv.y*w.y;
                s0 += qx; s1 += qx; s2 += qx; s3 += qx;
            }
        }
        ssb[u0 * 33 + v]        = fmaxf(s0, 0.f);
        ssb[(u0 + 8) * 33 + v]  = fmaxf(s1, 0.f);
        ssb[(u0 + 16) * 33 + v] = fmaxf(s2, 0.f);
        ssb[(u0 + 24) * 33 + v] = fmaxf(s3, 0.f);
    }
    __syncthreads();
    // gg[u,q'] = sum_v ss[u,v] e^{-i q' v th};  real s => g[-q'] = conj(g[q'])
    {
        int u = tid >> 3, q = tid & 7;
        float gx = 0.f, gy = 0.f;
        for (int v = 0; v < 32; ++v) {
            float sv = ssb[u * 33 + v];
            float2 w = cs[(-(q * v)) & 31];
            gx += sv * w.x; gy += sv * w.y;
        }
        gg[u * 15 + 7 + q] = make_float2(gx, gy);
        if (q) gg[u * 15 + 7 - q] = make_float2(gx, -gy);
    }
    __syncthreads();
    // h[p',q'] = sum_u gg[u,q'] e^{-i p' u th};  h[-p',-q'] = conj(h[p',q'])
    if (tid < 113) {
        int ph, qh;
        if (tid < 105) { ph = 8 + tid / 15; qh = tid % 15; }
        else           { ph = 7; qh = 7 + (tid - 105); }
        int p = ph - 7;
        float hx = 0.f, hy = 0.f;
        for (int u = 0; u < 32; ++u) {
            float2 gv = gg[u * 15 + qh];
            float2 w = cs[(-(p * u)) & 31];
            hx += gv.x * w.x - gv.y * w.y;
            hy += gv.x * w.y + gv.y * w.x;
        }
        float2* outp = xmn + ((size_t)((b * 32 + f) * 32 + j)) * 225;
        outp[ph * 15 + qh] = make_float2(hx, hy);
        if (ph > 7 || qh > 7)
            outp[(14 - ph) * 15 + (14 - qh)] = make_float2(hx, -hy);
    }
}

// ---------- K34: fused xh2 + U, block per (b,c); direct coalesced global reads ----------
__global__ __launch_bounds__(256) void k34_U(const float* __restrict__ ws,
                                             const float2* __restrict__ xmn,
                                             float2* __restrict__ U) {
    __shared__ float2 xh2s[1800];          // 14400 B
    __shared__ float  S2s[1800];           // 7200 B
    int bc = blockIdx.x, tid = threadIdx.x;

    for (int i = tid; i < 1800; i += 256) S2s[i] = ws[OFF_S2 + i];

    float2 acc[8];
#pragma unroll
    for (int l = 0; l < 8; ++l) acc[l] = make_float2(0.f, 0.f);
    if (tid < 225) {
        const float2* xp = xmn + (size_t)bc * 7200;
        const float4* dw = (const float4*)(ws + OFF_D2F);
        for (int j = 0; j < 32; ++j) {
            float2 xv = xp[j * 225 + tid];
            float4 dA = dw[(j * 225 + tid) * 2];
            float4 dB = dw[(j * 225 + tid) * 2 + 1];
            acc[0].x += dA.x * xv.x; acc[0].y += dA.x * xv.y;
            acc[1].x += dA.y * xv.x; acc[1].y += dA.y * xv.y;
            acc[2].x += dA.z * xv.x; acc[2].y += dA.z * xv.y;
            acc[3].x += dA.w * xv.x; acc[3].y += dA.w * xv.y;
            acc[4].x += dB.x * xv.x; acc[4].y += dB.x * xv.y;
            acc[5].x += dB.y * xv.x; acc[5].y += dB.y * xv.y;
            acc[6].x += dB.z * xv.x; acc[6].y += dB.z * xv.y;
            acc[7].x += dB.w * xv.x; acc[7].y += dB.w * xv.y;
        }
#pragma unroll
        for (int l = 0; l < 8; ++l) xh2s[l * 225 + tid] = acc[l];
    }
    __syncthreads();

    for (int idx = tid; idx < 1800; idx += 256) {
        int l = idx / 225;
        int rem = idx - l * 225;
        int n = rem / 15, k = rem - n * 15;
        float2 a = make_float2(0.f, 0.f);
        for (int m = 0; m < 15; ++m) {
            float s = S2s[(l * 15 + m) * 15 + n];
            float2 v = xh2s[l * 225 + m * 15 + k];
            a.x += s * v.x;
            a.y += s * v.y;
        }
        U[(size_t)bc * 1800 + idx] = a;
    }
}

// ---------- K5: block per (c,l,fc); U & W staged once, single barrier ----------
__global__ __launch_bounds__(256) void k5_feat(const float* __restrict__ w2r,
                                               const float* __restrict__ w2i,
                                               const float2* __restrict__ U,
                                               float* __restrict__ feat) {
    __shared__ char ar[57600];
    float2* Us  = (float2*)ar;             // 16x225 f2 [b][t]
    float2* Wsh = (float2*)(ar + 28800);   // 16x225 f2 [fl][t]
    int bx = blockIdx.x;
    int c = bx >> 5, l = (bx >> 2) & 7, fc = bx & 3;
    int tid = threadIdx.x;

    for (int i = tid; i < 3600; i += 256) {
        int b = i / 225, t = i - b * 225;
        Us[i] = U[(size_t)(b * 32 + c) * 1800 + l * 225 + t];
    }
    for (int i = tid; i < 3600; i += 256) {
        int f = fc * 16 + i / 225;
        int t = i % 225;
        int n = t / 15, k = t - n * 15;
        bool valid = (iabs_(n - 7) <= l) && (iabs_(k - 7) <= l);
        int wi = ((c * 64 + f) * 8 + l) * 225 + t;
        Wsh[i] = valid ? make_float2(w2r[wi], w2i[wi]) : make_float2(0.f, 0.f);
    }
    __syncthreads();
    int b = tid >> 4, fl = tid & 15;
    float accv = 0.f;
    const float2* up = Us + b * 225;
    const float2* wp = Wsh + fl * 225;
    for (int t = 0; t < 225; ++t)
        accv += up[t].x * wp[t].x + up[t].y * wp[t].y;
    atomicAdd(&feat[b * 64 + fc * 16 + fl], accv);
}

// ---------------- K6: relu(feat) -> conv1d + relu + BN + fc ----------------
__global__ __launch_bounds__(640) void k6_head(const float* __restrict__ feat,
                                               const float* __restrict__ w3,
                                               const float* __restrict__ b3,
                                               const float* __restrict__ gamma,
                                               const float* __restrict__ beta,
                                               const float* __restrict__ fcw,
                                               const float* __restrict__ fcb,
                                               float* __restrict__ out) {
    __shared__ float fL[1024];
    __shared__ float w3L[80];
    __shared__ float b3L[10];
    __shared__ float r3[9120];
    __shared__ float scaleL[10], shiftL[10];
    int tid = threadIdx.x;
    for (int i = tid; i < 1024; i += 640) fL[i] = fmaxf(feat[i], 0.f);
    if (tid < 80) w3L[tid] = w3[tid];
    if (tid >= 80 && tid < 90) b3L[tid - 80] = b3[tid - 80];
    __syncthreads();
    for (int i = tid; i < 9120; i += 640) {
        int ch = i / 912;
        int r = i % 912;
        int b = r / 57, pos = r % 57;
        float acc = b3L[ch];
#pragma unroll
        for (int t = 0; t < 8; ++t) acc += fL[b * 64 + pos + t] * w3L[ch * 8 + t];
        r3[ch * 912 + r] = fmaxf(acc, 0.0f);
    }
    __syncthreads();
    int wave = tid >> 6, lane = tid & 63;
    if (wave < 10) {
        float s = 0.f, s2 = 0.f;
        for (int i = lane; i < 912; i += 64) {
            float v = r3[wave * 912 + i];
            s += v;
            s2 += v * v;
        }
        for (int off = 32; off > 0; off >>= 1) {
            s += __shfl_down(s, off);
            s2 += __shfl_down(s2, off);
        }
        if (lane == 0) {
            float mu = s / 912.0f;
            float var = s2 / 912.0f - mu * mu;
            float sc = gamma[wave] * rsqrtf(var + 1e-5f);
            scaleL[wave] = sc;
            shiftL[wave] = beta[wave] - mu * sc;
        }
    }
    __syncthreads();
    {   // out[b,o]: 4 lanes per (b,o) pair
        int pair = tid >> 2, sub = tid & 3;
        int b = pair / 10, o = pair % 10;
        float acc = 0.f;
        for (int idx = sub; idx < 570; idx += 4) {
            int ch = idx / 57, pos = idx - ch * 57;
            acc += (r3[ch * 912 + b * 57 + pos] * scaleL[ch] + shiftL[ch])
                   * fcw[o * 570 + idx];
        }
        acc += __shfl_down(acc, 2);
        acc += __shfl_down(acc, 1);
        if (sub == 0) out[b * 10 + o] = acc + fcb[o];
    }
}

extern "C" void kernel_launch(void* const* d_in, const int* in_sizes, int n_in,
                              void* d_out, int out_size, void* d_ws, size_t ws_size,
                              hipStream_t stream) {
    const float* x   = (const float*)d_in[0];
    const float* w1r = (const float*)d_in[1];
    const float* w1i = (const float*)d_in[2];
    const float* w2r = (const float*)d_in[3];
    const float* w2i = (const float*)d_in[4];
    const float* c3w = (const float*)d_in[5];
    const float* c3b = (const float*)d_in[6];
    const float* bng = (const float*)d_in[7];
    const float* bnb = (const float*)d_in[8];
    const float* fcw = (const float*)d_in[9];
    const float* fcb = (const float*)d_in[10];
    float* ws = (float*)d_ws;
    float* out = (float*)d_out;

    hipLaunchKernelGGL(k0a_tables, dim3(1), dim3(256), 0, stream, ws);
    hipLaunchKernelGGL(k0_consts, dim3(2341), dim3(256), 0, stream, ws);
    hipLaunchKernelGGL(k1_xh, dim3(4, 16), dim3(256), 0, stream, x, ws,
                       (float2*)(ws + OFF_XH));
    hipLaunchKernelGGL(k2_planes, dim3(32, 32, 16), dim3(256), 0, stream, w1r, w1i, ws,
                       (float2*)(ws + OFF_XMN));
    hipLaunchKernelGGL(k34_U, dim3(512), dim3(256), 0, stream, ws,
                       (const float2*)(ws + OFF_XMN), (float2*)(ws + OFF_U));
    hipLaunchKernelGGL(k5_feat, dim3(1024), dim3(256), 0, stream, w2r, w2i,
                       (const float2*)(ws + OFF_U), ws + OFF_FEAT);
    hipLaunchKernelGGL(k6_head, dim3(1), dim3(640), 0, stream, ws + OFF_FEAT,
                       c3w, c3b, bng, bnb, fcw, fcb, out);
}

// Round 5
// 320.168 us; speedup vs baseline: 2.0981x; 1.1335x over previous
//
#include <hip/hip_runtime.h>
#include <math.h>

#ifndef M_PI
#define M_PI 3.14159265358979323846
#endif

// ---------------- workspace layout (float offsets) ----------------
// double tables (k0a): [0..353] doubles at float offset 0 (708 floats, pad 720)
//   LFd[64] | w0d[64]@64 | w1qd[32]@128 | cb0[64]@160 | sb0[64]@224
//   cb1[32]@288 | sb1[32]@320 | cb2s@352 | sb2s@353
#define OFF_TRIG 708              // float2 cs32[32] then cs64[64]  (192 floats)
#define OFF_D1F 900               // [16][64][31]                 31744
#define OFF_D1I 32644             // D1IT: [j=32][mh=31][l=16][nh=32]  507904
#define OFF_D2F 540548            // D2FT: [j=32][pq=225][l=8]    57600
#define OFF_S2  598148            // [8][15][15]                   1800
#define OFF_XH  599948            // float2 [16][16*31]           15872 floats
#define OFF_XMN 615820            // float2 [16][32][32][225]   7372800 floats
#define OFF_U   7988620           // float2 [16*32][8][225]     1843200 floats
#define OFF_FEAT 9831820          // [16][64]                      1024 floats

static __device__ __forceinline__ int iabs_(int v) { return v < 0 ? -v : v; }

static __device__ __forceinline__ double powi_d(double x, int e) {
    double r = 1.0;
    while (e) { if (e & 1) r *= x; x *= x; e >>= 1; }
    return r;
}

// ---------------- K0a: tiny table precompute (1 block) + feat zero ----------------
__global__ __launch_bounds__(256) void k0a_tables(float* __restrict__ ws) {
    double* T = (double*)ws;
    int t = threadIdx.x;
    __shared__ double lg[64];
    if (t < 64) lg[t] = (t == 0) ? 0.0 : log((double)t);
    __syncthreads();
    if (t == 0) {
        double s = 0.0;
        for (int i = 0; i < 64; ++i) { s += lg[i]; T[i] = s; }   // LF[i]=log(i!)
    }
    if (t < 64) {                       // w0 quad weights (B0=32) + half-angle trig
        double beta = M_PI * (2.0 * t + 1.0) / 128.0;
        double s = 0.0;
        for (int k = 0; k < 32; ++k) s += sin((2.0 * k + 1.0) * beta) / (2.0 * k + 1.0);
        T[64 + t] = 2.0 / 32.0 * sin(beta) * s;
        T[160 + t] = cos(0.5 * beta);
        T[224 + t] = sin(0.5 * beta);
    }
    if (t >= 64 && t < 96) {            // w1q quad weights (B1=16) + half-angle trig
        int j = t - 64;
        double beta = M_PI * (2.0 * j + 1.0) / 64.0;
        double s = 0.0;
        for (int k = 0; k < 16; ++k) s += sin((2.0 * k + 1.0) * beta) / (2.0 * k + 1.0);
        T[128 + j] = 2.0 / 16.0 * sin(beta) * s;
        T[288 + j] = cos(0.5 * beta);
        T[320 + j] = sin(0.5 * beta);
    }
    if (t == 96) {                      // beta2[0] = pi/32 half-angle
        T[352] = cos(M_PI / 64.0);
        T[353] = sin(M_PI / 64.0);
    }
    float2* F = (float2*)(ws + OFF_TRIG);
    if (t < 32) {
        double a = 2.0 * M_PI * (double)t / 32.0;
        F[t] = make_float2((float)cos(a), (float)sin(a));
    }
    if (t >= 128 && t < 192) {
        int i = t - 128;
        double a = 2.0 * M_PI * (double)i / 64.0;
        F[32 + i] = make_float2((float)cos(a), (float)sin(a));
    }
    for (int i = t; i < 1024; i += 256) ws[OFF_FEAT + i] = 0.f;   // feat zero
}

// ---------------- K0: build Wigner constant tables ----------------
__device__ double wig_fast(int l, int m, int n, double cb, double sb, const double* LF) {
    int kmin = max(0, m - n), kmax = min(l + m, l - n);
    if (kmax < kmin) return 0.0;
    double lc = 0.5 * (LF[l + m] + LF[l - m] + LF[l + n] + LF[l - n])
              - LF[kmin] - LF[l + m - kmin] - LF[l - n - kmin] - LF[n - m + kmin];
    double t = exp(lc) * powi_d(cb, 2 * l + m - n - 2 * kmin)
                       * powi_d(sb, n - m + 2 * kmin);
    if (kmin & 1) t = -t;
    double ratio = (sb * sb) / (cb * cb);
    double s = t;
    for (int k = kmin; k < kmax; ++k) {
        t *= -(((double)(l + m - k) * (double)(l - n - k)) /
               ((double)(k + 1) * (double)(n - m + k + 1))) * ratio;
        s += t;
    }
    return s;
}

__global__ __launch_bounds__(256) void k0_consts(float* __restrict__ ws) {
    const double* T = (const double*)ws;
    __shared__ double LF[64];
    int tid = threadIdx.x;
    if (tid < 64) LF[tid] = T[tid];
    __syncthreads();
    int gid = blockIdx.x * 256 + tid;
    if (gid >= 599048) return;

    if (gid < 31744) {                       // D1F [l][j][mh]
        int mh = gid % 31, j = (gid / 31) % 64, l = gid / (31 * 64);
        int m = mh - 15;
        double v = 0.0;
        if (iabs_(m) <= l)
            v = T[64 + j] * wig_fast(l, m, 0, T[160 + j], T[224 + j], LF);
        ws[OFF_D1F + gid] = (float)v;
    } else if (gid < 539648) {               // D1IT [j][mh][l][nh32]
        int r = gid - 31744;
        int nh = r & 31;
        int l  = (r >> 5) & 15;
        int mh = (r >> 9) % 31;
        int j  = r / (512 * 31);
        int m = mh - 15, n = nh - 15;
        double v = 0.0;
        if (nh < 31 && iabs_(m) <= l && iabs_(n) <= l)
            v = (2.0 * l + 1.0) * wig_fast(l, m, n, T[288 + j], T[320 + j], LF);
        ws[OFF_D1I + r] = (float)v;
    } else if (gid < 597248) {               // D2FT [j][pq][l]
        int r = gid - 539648;
        int l = r & 7;
        int pq = (r >> 3) % 225;
        int j = r / 1800;
        int mh = pq / 15, nh = pq % 15;
        int m = mh - 7, n = nh - 7;
        double v = 0.0;
        if (iabs_(m) <= l && iabs_(n) <= l)
            v = T[128 + j] * wig_fast(l, m, n, T[288 + j], T[320 + j], LF);
        ws[OFF_D2F + r] = (float)v;
    } else {                                 // S2 = D2I[:,0,:,:]
        int r = gid - 597248;
        int nh = r % 15, mh = (r / 15) % 15, l = r / 225;
        int m = mh - 7, n = nh - 7;
        double v = 0.0;
        if (iabs_(m) <= l && iabs_(n) <= l)
            v = (2.0 * l + 1.0) * wig_fast(l, m, n, T[352], T[353], LF);
        ws[OFF_S2 + r] = (float)v;
    }
}

// ---------------- K1: x -> xm -> xh ----------------
__global__ __launch_bounds__(256) void k1_xh(const float* __restrict__ x,
                                             const float* __restrict__ ws,
                                             float2* __restrict__ xh) {
    __shared__ float  xs[64 * 64];
    __shared__ float2 xm[64 * 8];
    __shared__ float2 cs64[64];
    int c = blockIdx.x, b = blockIdx.y, tid = threadIdx.x;
    int mh0 = c * 8;
    int cnt = min(8, 31 - mh0);
    for (int i = tid; i < 4096; i += 256) xs[i] = x[b * 4096 + i];
    if (tid < 64) cs64[tid] = ((const float2*)(ws + OFF_TRIG))[32 + tid];
    __syncthreads();
    for (int i = tid; i < 512; i += 256) {
        int j = i >> 3, mi = i & 7;
        if (mi < cnt) {
            int mu = mh0 + mi - 15;
            float re = 0.f, im = 0.f;
            for (int t = 0; t < 64; ++t) {
                float2 w = cs64[(mu * t) & 63];
                float xv = xs[j * 64 + t];
                re += xv * w.x;
                im -= xv * w.y;
            }
            xm[i] = make_float2(re, im);
        }
    }
    __syncthreads();
    const float* D1F = ws + OFF_D1F;
    if (tid < 128) {
        int l = tid >> 3, mi = tid & 7;
        if (mi < cnt) {
            int mh = mh0 + mi;
            float re = 0.f, im = 0.f;
            for (int j = 0; j < 64; ++j) {
                float d = D1F[(l * 64 + j) * 31 + mh];
                float2 v = xm[j * 8 + mi];
                re += d * v.x;
                im += d * v.y;
            }
            xh[b * 496 + l * 31 + mh] = make_float2(re, im);
        }
    }
}

// ------- K2: per-(b,f,j) plane; Hermitian-half iDFT2 + relu + fwd DFT2 -------
__global__ __launch_bounds__(256) void k2_planes(const float* __restrict__ w1r,
                                                 const float* __restrict__ w1i,
                                                 const float* __restrict__ ws,
                                                 float2* __restrict__ xmn) {
    __shared__ char ar[16896];
    __shared__ float2 cs[32];
    float2* As  = (float2*)ar;              // 496 f2 @0           (f1 phase)
    float2* Wc  = (float2*)(ar + 4096);     // 16x32 f2 @4096      (f1 phase)
    float2* f1  = (float2*)(ar + 8448);     // 31 rows stride34 f2 (dies after fH)
    float2* fH  = (float2*)ar;              // 16 rows stride34 f2 @0 [0,4352)
    float2* tls = (float2*)(ar + 4608);     // 17 rows stride33 f2 [4608,9096)
    float*  ssb = (float*)(ar + 9216);      // 32x33 f [9216,13440)
    float2* gg  = (float2*)ar;              // 32x15 f2 @0

    int j = blockIdx.x, f = blockIdx.y, b = blockIdx.z;
    int tid = threadIdx.x;
    const float2* xh = (const float2*)(ws + OFF_XH);

    if (tid < 32) cs[tid] = ((const float2*)(ws + OFF_TRIG))[tid];
    for (int i = tid; i < 496; i += 256) As[i] = xh[b * 496 + i];
    for (int i = tid; i < 512; i += 256) {
        int l = i >> 5, nh = i & 31;
        float mask = (nh < 31 && iabs_(nh - 15) <= l) ? 1.0f : 0.0f;
        int src = f * 496 + l * 31 + min(nh, 30);
        Wc[i] = make_float2(w1r[src] * mask, -w1i[src] * mask);
    }
    __syncthreads();
    // ---- f1[m, nh0..nh0+3] = sum_l D1IT[j,m,l,nh] * A[l,m] * W[l,nh] ----
    {
        int mrow = tid >> 3;
        int nh0 = (tid & 7) * 4;
        if (mrow < 31) {
            int l0 = iabs_(mrow - 15);
            float2 a0 = {0,0}, a1 = {0,0}, a2 = {0,0}, a3 = {0,0};
            const float* Dbase = ws + OFF_D1I + ((j * 31 + mrow) * 16) * 32 + nh0;
            for (int l = l0; l < 16; ++l) {
                float2 a = As[l * 31 + mrow];
                float4 w01 = *(const float4*)(Wc + l * 32 + nh0);
                float4 w23 = *(const float4*)(Wc + l * 32 + nh0 + 2);
                float4 d = *(const float4*)(Dbase + l * 32);
                float t;
                t = a.x*w01.x - a.y*w01.y; a0.x += d.x*t;
                t = a.x*w01.y + a.y*w01.x; a0.y += d.x*t;
                t = a.x*w01.z - a.y*w01.w; a1.x += d.y*t;
                t = a.x*w01.w + a.y*w01.z; a1.y += d.y*t;
                t = a.x*w23.x - a.y*w23.y; a2.x += d.z*t;
                t = a.x*w23.y + a.y*w23.x; a2.y += d.z*t;
                t = a.x*w23.z - a.y*w23.w; a3.x += d.w*t;
                t = a.x*w23.w + a.y*w23.z; a3.y += d.w*t;
            }
            float2* fr = f1 + mrow * 34 + nh0;
            fr[0] = a0; fr[1] = a1; fr[2] = a2; fr[3] = a3;
        }
    }
    __syncthreads();
    // ---- fH[mm,nh] = 0.5*(f1[mm+15,nh] + conj(f1[15-mm,30-nh])), mm=0..15 ----
    for (int i = tid; i < 512; i += 256) {
        int mm = i >> 5, nh = i & 31;
        float2 v = make_float2(0.f, 0.f);
        if (nh < 31) {
            float2 a = f1[(mm + 15) * 34 + nh];
            float2 bb = f1[(15 - mm) * 34 + (30 - nh)];
            v = make_float2(0.5f * (a.x + bb.x), 0.5f * (a.y - bb.y));
        }
        fH[mm * 34 + nh] = v;
    }
    __syncthreads();
    // ---- t[mm,v] = sum_n fH[mm,n] e^{+i n v th}, v = v0+8k (i^{nk} signs) ----
    if (tid < 128) {
        int mm = tid >> 3, v0 = tid & 7;
        const float2* frow = fH + mm * 34;
        float2 a0 = {0,0}, a1 = {0,0}, a2 = {0,0}, a3 = {0,0};
        for (int nb = 0; nb < 32; nb += 4) {
            float4 q01 = *(const float4*)(frow + nb);
            float4 q23 = *(const float4*)(frow + nb + 2);
            { // n = nb-15, n mod 4 = 1
                float2 w = cs[((nb - 15) * v0) & 31];
                float px = q01.x*w.x - q01.y*w.y, py = q01.x*w.y + q01.y*w.x;
                a0.x += px; a0.y += py;  a1.x -= py; a1.y += px;
                a2.x -= px; a2.y -= py;  a3.x += py; a3.y -= px;
            }
            { // n mod 4 = 2
                float2 w = cs[((nb - 14) * v0) & 31];
                float px = q01.z*w.x - q01.w*w.y, py = q01.z*w.y + q01.w*w.x;
                a0.x += px; a0.y += py;  a1.x -= px; a1.y -= py;
                a2.x += px; a2.y += py;  a3.x -= px; a3.y -= py;
            }
            { // n mod 4 = 3
                float2 w = cs[((nb - 13) * v0) & 31];
                float px = q23.x*w.x - q23.y*w.y, py = q23.x*w.y + q23.y*w.x;
                a0.x += px; a0.y += py;  a1.x += py; a1.y -= px;
                a2.x -= px; a2.y -= py;  a3.x -= py; a3.y += px;
            }
            { // n mod 4 = 0
                float2 w = cs[((nb - 12) * v0) & 31];
                float px = q23.z*w.x - q23.w*w.y, py = q23.z*w.y + q23.w*w.x;
                a0.x += px; a0.y += py;  a1.x += px; a1.y += py;
                a2.x += px; a2.y += py;  a3.x += px; a3.y += py;
            }
        }
        float2* trow = tls + mm * 33;
        trow[v0] = a0; trow[v0 + 8] = a1; trow[v0 + 16] = a2; trow[v0 + 24] = a3;
    } else if (tid < 161) {
        tls[16 * 33 + (tid - 128)] = make_float2(0.f, 0.f);   // zero row 16
    }
    __syncthreads();
    // ---- ss[u,v] = relu( t[0,v].re + 2 sum_{m=1..15} Re(t[m,v] e^{imu th}) ) ----
    {
        int v = tid & 31, u0 = tid >> 5;
        float s0 = 0, s1 = 0, s2 = 0, s3 = 0;
        for (int mb = 0; mb < 4; ++mb) {
            int r1 = mb * 4 + 1;
            { // m mod 4 = 1
                float2 tv = tls[r1 * 33 + v];       float2 w = cs[(r1 * u0) & 31];
                float qx = tv.x*w.x - tv.y*w.y, qy = tv.x*w.y + tv.y*w.x;
                s0 += qx; s1 -= qy; s2 -= qx; s3 += qy;
            }
            { // m mod 4 = 2 (real part only)
                float2 tv = tls[(r1 + 1) * 33 + v]; float2 w = cs[((r1 + 1) * u0) & 31];
                float qx = tv.x*w.x - tv.y*w.y;
                s0 += qx; s1 -= qx; s2 += qx; s3 -= qx;
            }
            { // m mod 4 = 3
                float2 tv = tls[(r1 + 2) * 33 + v]; float2 w = cs[((r1 + 2) * u0) & 31];
                float qx = tv.x*w.x - tv.y*w.y, qy = tv.x*w.y + tv.y*w.x;
                s0 += qx; s1 += qy; s2 -= qx; s3 -= qy;
            }
            { // m mod 4 = 0
                float2 tv = tls[(r1 + 3) * 33 + v]; float2 w = cs[((r1 + 3) * u0) & 31];
                float qx = tv.x*w.x - tv.y*w.y;
                s0 += qx; s1 += qx; s2 += qx; s3 += qx;
            }
        }
        float t0x = tls[v].x;
        ssb[u0 * 33 + v]        = fmaxf(t0x + 2.f * s0, 0.f);
        ssb[(u0 + 8) * 33 + v]  = fmaxf(t0x + 2.f * s1, 0.f);
        ssb[(u0 + 16) * 33 + v] = fmaxf(t0x + 2.f * s2, 0.f);
        ssb[(u0 + 24) * 33 + v] = fmaxf(t0x + 2.f * s3, 0.f);
    }
    __syncthreads();
    // ---- gg[u,q'] = sum_v ss[u,v] e^{-i q' v th}, radix-4 over v ----
    {
        int u = tid >> 3, q = tid & 7;
        int qm = q & 3;
        float r1 = (qm == 0) ? 1.f : (qm == 2 ? -1.f : 0.f);
        float r2 = (qm & 1) ? -1.f : 1.f;
        float i1 = (qm == 1) ? -1.f : (qm == 3 ? 1.f : 0.f);
        float gx = 0.f, gy = 0.f;
        const float* srow = ssb + u * 33;
        for (int vb = 0; vb < 8; ++vb) {
            float s0 = srow[vb], s1 = srow[vb + 8], s2 = srow[vb + 16], s3 = srow[vb + 24];
            float zre = s0 + r1 * s1 + r2 * s2 + r1 * s3;
            float zim = i1 * (s1 - s3);
            float2 w = cs[(q * vb) & 31];       // e^{-iqvb} = (w.x, -w.y)
            gx += zre * w.x + zim * w.y;
            gy += zim * w.x - zre * w.y;
        }
        gg[u * 15 + 7 + q] = make_float2(gx, gy);
        if (q) gg[u * 15 + 7 - q] = make_float2(gx, -gy);
    }
    __syncthreads();
    // ---- h[p',q'] = sum_u gg[u,q'] e^{-i p' u th};  h[-p',-q'] = conj ----
    if (tid < 113) {
        int ph, qh;
        if (tid < 105) { ph = 8 + tid / 15; qh = tid % 15; }
        else           { ph = 7; qh = 7 + (tid - 105); }
        int p = ph - 7;
        float hx = 0.f, hy = 0.f;
        for (int u = 0; u < 32; ++u) {
            float2 gv = gg[u * 15 + qh];
            float2 w = cs[(-(p * u)) & 31];
            hx += gv.x * w.x - gv.y * w.y;
            hy += gv.x * w.y + gv.y * w.x;
        }
        float2* outp = xmn + ((size_t)((b * 32 + f) * 32 + j)) * 225;
        outp[ph * 15 + qh] = make_float2(hx, hy);
        if (ph > 7 || qh > 7)
            outp[(14 - ph) * 15 + (14 - qh)] = make_float2(hx, -hy);
    }
}

// ---------- K34: fused xh2 + U, block per (b,c); direct coalesced global reads ----------
__global__ __launch_bounds__(256) void k34_U(const float* __restrict__ ws,
                                             const float2* __restrict__ xmn,
                                             float2* __restrict__ U) {
    __shared__ float2 xh2s[1800];
    __shared__ float  S2s[1800];
    int bc = blockIdx.x, tid = threadIdx.x;

    for (int i = tid; i < 1800; i += 256) S2s[i] = ws[OFF_S2 + i];

    float2 acc[8];
#pragma unroll
    for (int l = 0; l < 8; ++l) acc[l] = make_float2(0.f, 0.f);
    if (tid < 225) {
        const float2* xp = xmn + (size_t)bc * 7200;
        const float4* dw = (const float4*)(ws + OFF_D2F);
        for (int j = 0; j < 32; ++j) {
            float2 xv = xp[j * 225 + tid];
            float4 dA = dw[(j * 225 + tid) * 2];
            float4 dB = dw[(j * 225 + tid) * 2 + 1];
            acc[0].x += dA.x * xv.x; acc[0].y += dA.x * xv.y;
            acc[1].x += dA.y * xv.x; acc[1].y += dA.y * xv.y;
            acc[2].x += dA.z * xv.x; acc[2].y += dA.z * xv.y;
            acc[3].x += dA.w * xv.x; acc[3].y += dA.w * xv.y;
            acc[4].x += dB.x * xv.x; acc[4].y += dB.x * xv.y;
            acc[5].x += dB.y * xv.x; acc[5].y += dB.y * xv.y;
            acc[6].x += dB.z * xv.x; acc[6].y += dB.z * xv.y;
            acc[7].x += dB.w * xv.x; acc[7].y += dB.w * xv.y;
        }
#pragma unroll
        for (int l = 0; l < 8; ++l) xh2s[l * 225 + tid] = acc[l];
    }
    __syncthreads();

    for (int idx = tid; idx < 1800; idx += 256) {
        int l = idx / 225;
        int rem = idx - l * 225;
        int n = rem / 15, k = rem - n * 15;
        float2 a = make_float2(0.f, 0.f);
        for (int m = 0; m < 15; ++m) {
            float s = S2s[(l * 15 + m) * 15 + n];
            float2 v = xh2s[l * 225 + m * 15 + k];
            a.x += s * v.x;
            a.y += s * v.y;
        }
        U[(size_t)bc * 1800 + idx] = a;
    }
}

// ---------- K5: block per (c,l,fc); U & W staged once, single barrier ----------
__global__ __launch_bounds__(256) void k5_feat(const float* __restrict__ w2r,
                                               const float* __restrict__ w2i,
                                               const float2* __restrict__ U,
                                               float* __restrict__ feat) {
    __shared__ char ar[57600];
    float2* Us  = (float2*)ar;
    float2* Wsh = (float2*)(ar + 28800);
    int bx = blockIdx.x;
    int c = bx >> 5, l = (bx >> 2) & 7, fc = bx & 3;
    int tid = threadIdx.x;

    for (int i = tid; i < 3600; i += 256) {
        int b = i / 225, t = i - b * 225;
        Us[i] = U[(size_t)(b * 32 + c) * 1800 + l * 225 + t];
    }
    for (int i = tid; i < 3600; i += 256) {
        int f = fc * 16 + i / 225;
        int t = i % 225;
        int n = t / 15, k = t - n * 15;
        bool valid = (iabs_(n - 7) <= l) && (iabs_(k - 7) <= l);
        int wi = ((c * 64 + f) * 8 + l) * 225 + t;
        Wsh[i] = valid ? make_float2(w2r[wi], w2i[wi]) : make_float2(0.f, 0.f);
    }
    __syncthreads();
    int b = tid >> 4, fl = tid & 15;
    float accv = 0.f;
    const float2* up = Us + b * 225;
    const float2* wp = Wsh + fl * 225;
    for (int t = 0; t < 225; ++t)
        accv += up[t].x * wp[t].x + up[t].y * wp[t].y;
    atomicAdd(&feat[b * 64 + fc * 16 + fl], accv);
}

// ---------------- K6: relu(feat) -> conv1d + relu + BN + fc ----------------
__global__ __launch_bounds__(640) void k6_head(const float* __restrict__ feat,
                                               const float* __restrict__ w3,
                                               const float* __restrict__ b3,
                                               const float* __restrict__ gamma,
                                               const float* __restrict__ beta,
                                               const float* __restrict__ fcw,
                                               const float* __restrict__ fcb,
                                               float* __restrict__ out) {
    __shared__ float fL[1024];
    __shared__ float w3L[80];
    __shared__ float b3L[10];
    __shared__ float r3[9120];
    __shared__ float scaleL[10], shiftL[10];
    int tid = threadIdx.x;
    for (int i = tid; i < 1024; i += 640) fL[i] = fmaxf(feat[i], 0.f);
    if (tid < 80) w3L[tid] = w3[tid];
    if (tid >= 80 && tid < 90) b3L[tid - 80] = b3[tid - 80];
    __syncthreads();
    for (int i = tid; i < 9120; i += 640) {
        int ch = i / 912;
        int r = i % 912;
        int b = r / 57, pos = r % 57;
        float acc = b3L[ch];
#pragma unroll
        for (int t = 0; t < 8; ++t) acc += fL[b * 64 + pos + t] * w3L[ch * 8 + t];
        r3[ch * 912 + r] = fmaxf(acc, 0.0f);
    }
    __syncthreads();
    int wave = tid >> 6, lane = tid & 63;
    if (wave < 10) {
        float s = 0.f, s2 = 0.f;
        for (int i = lane; i < 912; i += 64) {
            float v = r3[wave * 912 + i];
            s += v;
            s2 += v * v;
        }
        for (int off = 32; off > 0; off >>= 1) {
            s += __shfl_down(s, off);
            s2 += __shfl_down(s2, off);
        }
        if (lane == 0) {
            float mu = s / 912.0f;
            float var = s2 / 912.0f - mu * mu;
            float sc = gamma[wave] * rsqrtf(var + 1e-5f);
            scaleL[wave] = sc;
            shiftL[wave] = beta[wave] - mu * sc;
        }
    }
    __syncthreads();
    {
        int pair = tid >> 2, sub = tid & 3;
        int b = pair / 10, o = pair % 10;
        float acc = 0.f;
        for (int idx = sub; idx < 570; idx += 4) {
            int ch = idx / 57, pos = idx - ch * 57;
            acc += (r3[ch * 912 + b * 57 + pos] * scaleL[ch] + shiftL[ch])
                   * fcw[o * 570 + idx];
        }
        acc += __shfl_down(acc, 2);
        acc += __shfl_down(acc, 1);
        if (sub == 0) out[b * 10 + o] = acc + fcb[o];
    }
}

extern "C" void kernel_launch(void* const* d_in, const int* in_sizes, int n_in,
                              void* d_out, int out_size, void* d_ws, size_t ws_size,
                              hipStream_t stream) {
    const float* x   = (const float*)d_in[0];
    const float* w1r = (const float*)d_in[1];
    const float* w1i = (const float*)d_in[2];
    const float* w2r = (const float*)d_in[3];
    const float* w2i = (const float*)d_in[4];
    const float* c3w = (const float*)d_in[5];
    const float* c3b = (const float*)d_in[6];
    const float* bng = (const float*)d_in[7];
    const float* bnb = (const float*)d_in[8];
    const float* fcw = (const float*)d_in[9];
    const float* fcb = (const float*)d_in[10];
    float* ws = (float*)d_ws;
    float* out = (float*)d_out;

    hipLaunchKernelGGL(k0a_tables, dim3(1), dim3(256), 0, stream, ws);
    hipLaunchKernelGGL(k0_consts, dim3(2341), dim3(256), 0, stream, ws);
    hipLaunchKernelGGL(k1_xh, dim3(4, 16), dim3(256), 0, stream, x, ws,
                       (float2*)(ws + OFF_XH));
    hipLaunchKernelGGL(k2_planes, dim3(32, 32, 16), dim3(256), 0, stream, w1r, w1i, ws,
                       (float2*)(ws + OFF_XMN));
    hipLaunchKernelGGL(k34_U, dim3(512), dim3(256), 0, stream, ws,
                       (const float2*)(ws + OFF_XMN), (float2*)(ws + OFF_U));
    hipLaunchKernelGGL(k5_feat, dim3(1024), dim3(256), 0, stream, w2r, w2i,
                       (const float2*)(ws + OFF_U), ws + OFF_FEAT);
    hipLaunchKernelGGL(k6_head, dim3(1), dim3(640), 0, stream, ws + OFF_FEAT,
                       c3w, c3b, bng, bnb, fcw, fcb, out);
}